// Round 12
// baseline (590.707 us; speedup 1.0000x reference)
//
#include <hip/hip_runtime.h>
#include <hip/hip_bf16.h>

// Problem constants
#define N_NODES 10000
#define N_EDGES 64000
#define IN_F    1247
#define KPAD    1280   // IN_F padded to mult of 32
#define NH      4
#define D0      256
#define D1      8
#define HD0     1024   // NH*D0
#define HD1     32     // NH*D1
#define NBIG    3072   // Wl0 | Wr0 | Wres0
#define OUTF    6
#define INV_N   (1.0f / 10000.0f)
#define MPAD    10240  // 40 row-tiles of 256

typedef __attribute__((ext_vector_type(8))) short bf16x8;
typedef __attribute__((ext_vector_type(4))) float f32x4;
typedef unsigned int u32;

// async 16B global -> LDS (DMA). LDS dest: wave-uniform base + lane*16.
__device__ __forceinline__ void async_copy16(const unsigned short* gsrc,
                                             unsigned short* ldst) {
    __builtin_amdgcn_global_load_lds(
        (const __attribute__((address_space(1))) u32*)(gsrc),
        (__attribute__((address_space(3))) u32*)(ldst), 16, 0, 0);
}

// ---------------- workspace layout (float-slot offsets) ----------------
constexpr size_t OFF_FLAG   = 0;                          // 16
constexpr size_t OFF_COLSUM = 16;                         // 1280
constexpr size_t OFF_MASKM  = 1296;                       // 1280
constexpr size_t OFF_Z      = 2576;                       // N*32
constexpr size_t OFF_H3     = OFF_Z    + 320000;          // N*32
constexpr size_t OFF_OUT0   = OFF_H3   + 320000;          // bf16 N*1024 (res+bias)
constexpr size_t OFF_FS1    = OFF_OUT0 + 10240000;        // N*32
constexpr size_t OFF_FD1    = OFF_FS1  + 320000;          // N*32
constexpr size_t OFF_OUT1   = OFF_FD1  + 320000;          // N*32
constexpr size_t OFF_B0F    = OFF_OUT1 + 320000;          // 1024
constexpr size_t OFF_B1F    = OFF_B0F  + 1024;            // 64
constexpr size_t OFF_DEG    = OFF_B1F  + 64;              // int 10016
constexpr size_t OFF_ROWPTR = OFF_DEG  + 10016;           // int 10016
constexpr size_t OFF_CURSOR = OFF_ROWPTR + 10016;         // int 10016
constexpr size_t OFF_CSRE   = OFF_CURSOR + 10016;         // int 64000
constexpr size_t OFF_FS0B   = OFF_CSRE + 64000;           // bf16 N*1024
constexpr size_t OFF_FD0B   = OFF_FS0B + 5120000;         // bf16 N*1024 (reused as out0b)
constexpr size_t OFF_ABF    = OFF_FD0B + 5120000;         // bf16 MPAD*KPAD (dead after big GEMM;
                                                          //  reused as fs1b/fd1b/out1b partials)
constexpr size_t OFF_BT     = OFF_ABF  + 6553600;         // bf16 3072*KPAD (+dead tail)
constexpr size_t OFF_BT1    = OFF_BT   + 2048000;         // bf16 96*1024
constexpr size_t WS_FLOATS  = OFF_BT1  + 49152;

// dual-dtype load: is_f32 ? float : bf16
__device__ __forceinline__ float ldin(const void* p, size_t i, int f32) {
    return f32 ? ((const float*)p)[i]
               : __bfloat162float(((const __hip_bfloat16*)p)[i]);
}
__device__ __forceinline__ float bfu2f(unsigned short u) {
    union { unsigned int i; float f; } x;
    x.i = ((unsigned int)u) << 16;
    return x.f;
}
__device__ __forceinline__ unsigned short f2bu(float v) {
    __hip_bfloat16 h = __float2bfloat16(v);
    unsigned short u;
    __builtin_memcpy(&u, &h, 2);
    return u;
}

// ---------------- kernels ----------------

// fused init: detect dtype (64 blocks) + zero deg (40)
__global__ void init_kernel(const unsigned short* __restrict__ feats_w,
                            int* __restrict__ flag, int* __restrict__ deg) {
    int b = blockIdx.x, t = threadIdx.x;
    if (b < 64) {
        int found = 0;
        for (int i = b * 256 + t; i < 131072; i += 64 * 256)
            if (((feats_w[i] >> 7) & 0xFF) == 0xFF) found = 1;
        if (found) atomicOr(flag, 1);
    } else {
        int idx = (b - 64) * 256 + t;
        if (idx < N_NODES + 16) deg[idx] = 0;
    }
}

// fused: colsum (500 blocks, 100 rows each) + deg histogram (250) + smallprep (5)
__global__ void prepA_kernel(const void* __restrict__ feats, const int* __restrict__ dst,
                             const void* __restrict__ tm, const void* __restrict__ am,
                             const void* __restrict__ vm, const void* __restrict__ b0,
                             const void* __restrict__ b1,
                             float* __restrict__ colsum, int* __restrict__ deg,
                             float* __restrict__ maskmul, float* __restrict__ b0f,
                             float* __restrict__ b1f, const int* __restrict__ dflag) {
    int b = blockIdx.x, t = threadIdx.x;
    if (b < 500) {
        int f32 = *dflag;
        int c = (b % 5) * 256 + t;
        if (c >= IN_F) return;
        int r0 = (b / 5) * 100;
        float s = 0.f;
        for (int r = r0; r < r0 + 100; ++r)
            s += ldin(feats, (size_t)r * IN_F + c, f32);
        atomicAdd(&colsum[c], s);
    } else if (b < 750) {
        int e = (b - 500) * 256 + t;
        if (e < N_EDGES) atomicAdd(&deg[dst[e]], 1);
    } else {
        int f32 = *dflag;
        int c = (b - 750) * 256 + t;
        if (c < IN_F) maskmul[c] = ldin(tm, c, f32) + ldin(am, c, f32) + ldin(vm, c, f32);
        if (c < HD0) b0f[c] = ldin(b0, c, f32);
        if (c < HD1) b1f[c] = ldin(b1, c, f32);
    }
}

// block-wide exclusive scan via wave shfl scan (no serial thread-0 loop)
__global__ __launch_bounds__(256) void scan_kernel(const int* __restrict__ deg,
                                                   int* __restrict__ rowptr,
                                                   int* __restrict__ cursor) {
    __shared__ int wtot[4];
    int t = threadIdx.x;
    int lane = t & 63, w = t >> 6;
    int base = t * 40;
    int s = 0;
    for (int i = 0; i < 40; ++i) {
        int idx = base + i;
        if (idx < N_NODES) s += deg[idx];
    }
    int inc = s;
#pragma unroll
    for (int d = 1; d < 64; d <<= 1) {
        int v = __shfl_up(inc, d);
        if (lane >= d) inc += v;
    }
    if (lane == 63) wtot[w] = inc;
    __syncthreads();
    int woff = 0;
    for (int ww = 0; ww < w; ++ww) woff += wtot[ww];
    int run = woff + inc - s;          // exclusive prefix for this thread
    for (int i = 0; i < 40; ++i) {
        int idx = base + i;
        if (idx < N_NODES) {
            rowptr[idx] = run; cursor[idx] = run;
            run += deg[idx];
        }
    }
    if (t == 255) rowptr[N_NODES] = woff + inc;   // grand total
}

__global__ void scatter_kernel(const int* __restrict__ dst, int* __restrict__ cursor,
                               int* __restrict__ csr_eid) {
    int e = blockIdx.x * 256 + threadIdx.x;
    if (e >= N_EDGES) return;
    int pos = atomicAdd(&cursor[dst[e]], 1);
    csr_eid[pos] = e;
}

// fused big prep: prep_row+z (2560 blocks x 4 rows) + bt transpose (3840) +
// bt1 (384).  prep_row: wave per row, zero barriers.  z = v_f32 @ W2 computed
// IN-PLACE (row cached in LDS, 64 lanes x one (h,o) output x half-K each +
// shfl_xor(32) combine) -- removes the z strip from the big GEMM entirely
// (R10: z-tail made GEMM wall T+2Tz=144us instead of 2T=124) and is MORE
// accurate than the old bf16 path (f32 row pre-rounding).  Same-wave LDS
// write->read needs no barrier (per-wave LDS ordering).
__global__ __launch_bounds__(256) void prepB_kernel(
        const void* __restrict__ feats, const float* __restrict__ colsum,
        const float* __restrict__ maskmul, __hip_bfloat16* __restrict__ abf,
        const void* __restrict__ Wl0, const void* __restrict__ Wr0,
        const void* __restrict__ Wres0, const void* __restrict__ W2,
        __hip_bfloat16* __restrict__ bt,
        const void* __restrict__ Wl1, const void* __restrict__ Wr1,
        const void* __restrict__ Wres1, __hip_bfloat16* __restrict__ bt1,
        float* __restrict__ z, const int* __restrict__ dflag) {
    __shared__ float smem[5120];   // 4 waves x 1280 f32 row cache (20KB)
    int b = blockIdx.x, t = threadIdx.x;
    int f32 = *dflag;
    if (b < 2560) {
        int w = t >> 6, lane = t & 63;
        int n = b * 4 + w;
        unsigned short* arow = (unsigned short*)abf + (size_t)n * KPAD;
        if (n >= N_NODES) {
#pragma unroll
            for (int j = 0; j < 20; ++j) arow[j * 64 + lane] = 0;
            return;
        }
        float* vlds = smem + w * 1280;
        float v[20];
        float s = 0.f;
#pragma unroll
        for (int j = 0; j < 20; ++j) {
            int c = j * 64 + lane;
            float f = (c < IN_F) ? ldin(feats, (size_t)n * IN_F + c, f32) : 0.f;
            float vv = (f != 0.0f) ? f
                     : ((c < IN_F) ? 0.5f * colsum[c] * INV_N : 0.f);  // 0.5*(h+h1)
            v[j] = vv;
            s += fabsf(vv);
        }
#pragma unroll
        for (int off = 32; off > 0; off >>= 1) s += __shfl_xor(s, off);
        float scale = 1.0f / fmaxf(s, 1e-12f);
#pragma unroll
        for (int j = 0; j < 20; ++j) {
            int c = j * 64 + lane;
            float vv = (c < IN_F) ? v[j] * scale * maskmul[c] : 0.f;
            arow[c] = f2bu(vv);
            vlds[c] = vv;
        }
        // ---- z[n][h,o] = sum_c v[c] * W2[h][c][o]  (f32) ----
        // lane = half*32 + out; halves split the c-range, shfl_xor(32) combines.
        int out = lane & 31, half = lane >> 5;
        int hh = out >> 3, oo = out & 7;
        int cbeg = half * 640;
        int cend = half ? IN_F : 640;
        float p0 = 0.f, p1 = 0.f, p2 = 0.f, p3 = 0.f;
        int c = cbeg;
        for (; c + 3 < cend; c += 4) {
            p0 += vlds[c]     * ldin(W2, ((size_t)hh * IN_F + c)     * D1 + oo, f32);
            p1 += vlds[c + 1] * ldin(W2, ((size_t)hh * IN_F + c + 1) * D1 + oo, f32);
            p2 += vlds[c + 2] * ldin(W2, ((size_t)hh * IN_F + c + 2) * D1 + oo, f32);
            p3 += vlds[c + 3] * ldin(W2, ((size_t)hh * IN_F + c + 3) * D1 + oo, f32);
        }
        for (; c < cend; ++c)
            p0 += vlds[c] * ldin(W2, ((size_t)hh * IN_F + c) * D1 + oo, f32);
        float part = (p0 + p1) + (p2 + p3);
        part += __shfl_xor(part, 32);
        if (lane < 32) z[(size_t)n * HD1 + out] = part;
    } else if (b < 2560 + 3840) {
        // LDS-tiled transpose of Wl0/Wr0/Wres0 -> bt rows 0..3071
        int b2 = b - 2560;
        int bz = b2 / 1280, rem = b2 - bz * 1280;
        int by = rem >> 5, bx = rem & 31;
        float (*tile)[33] = (float(*)[33])smem;
        int n0 = bx * 32, k0 = by * 32;
        const void* W = (bz == 0) ? Wl0 : (bz == 1) ? Wr0 : Wres0;
        int tx = t & 31, ty = t >> 5;
        for (int i = ty; i < 32; i += 8) {
            int k = k0 + i;
            tile[i][tx] = (k < IN_F) ? ldin(W, (size_t)k * HD0 + n0 + tx, f32) : 0.f;
        }
        __syncthreads();
        for (int i = ty; i < 32; i += 8)
            bt[(size_t)(bz * 1024 + n0 + i) * KPAD + k0 + tx] = __float2bfloat16(tile[tx][i]);
    } else {
        // bt1 [96][1024], coalesced writes
        int idx = (b - (2560 + 3840)) * 256 + t;
        if (idx >= 96 * HD0) return;
        int n = idx >> 10, k = idx & 1023;
        int seg = n >> 5, col = n & 31;
        const void* W = (seg == 0) ? Wl1 : (seg == 1) ? Wr1 : Wres1;
        bt1[idx] = __float2bfloat16(ldin(W, (size_t)k * HD1 + col, f32));
    }
}

// MFMA GEMM: C[MPAD x 3072] = abf @ bt^T.  CLEAN 480-block grid (40 row x 12
// col = 2 perfect occupancy rounds of 256+224; wall = 2T ~ 124us).  z strip
// moved to prepB (R10's in-kernel z branch cost +8 VGPR and a T+2Tz tail).
// Main path byte-identical to R8/R10: fine-interleave + counted vmcnt(4),
// 3-slot BK=32, 8 waves, XCD swizzle.
__global__ __launch_bounds__(512) void mfma_gemm(
        const unsigned short* __restrict__ A, const unsigned short* __restrict__ BT,
        const float* __restrict__ b0f, __hip_bfloat16* __restrict__ fs0b,
        __hip_bfloat16* __restrict__ fd0b, __hip_bfloat16* __restrict__ out0r) {
    __shared__ unsigned short As0[8192], Bs0[8192];   // slot 0 (16KB + 16KB)
    __shared__ unsigned short As1[8192], Bs1[8192];   // slot 1
    __shared__ unsigned short As2[8192], Bs2[8192];   // slot 2  (96KB)
    const int g = blockIdx.x;
    const int tid = threadIdx.x;
    const int wave = tid >> 6, lane = tid & 63;
    const int quad = lane >> 4, l16 = lane & 15;
    const int srow = lane & 15;
    const int skc  = (lane >> 4) * 8;

    // 480 blocks = 8 XCD x 60 (5 row x 12 col)
    const int xcd = g & 7, l = g >> 3;          // l in [0,60)
    const int colt = l / 5, rowi = l - colt * 5;
    const int bm = (xcd * 5 + rowi) * 256;
    const int bn = colt * 256;
    const int wr = wave >> 2, wc = wave & 3;    // 2 x 4 wave grid
    const int wm = wr * 128, wn = wc * 64;

    f32x4 acc[8][4];
#pragma unroll
    for (int i = 0; i < 8; ++i)
#pragma unroll
        for (int j = 0; j < 4; ++j) acc[i][j] = (f32x4){0.f, 0.f, 0.f, 0.f};

#define BARX() do { __builtin_amdgcn_s_barrier();                            \
                    __builtin_amdgcn_sched_barrier(0); } while (0)

#define STAGE_A2(kt, dst) do {                                               \
        _Pragma("unroll")                                                    \
        for (int tt = 0; tt < 2; ++tt) {                                     \
            int gg = wave + 8 * tt;                                          \
            async_copy16(A + (size_t)(bm + gg * 16 + srow) * KPAD            \
                             + (kt) + skc,                                   \
                         (dst) + gg * 512);                                  \
        } } while (0)

#define STAGE_B2(kt, dst) do {                                               \
        _Pragma("unroll")                                                    \
        for (int tt = 0; tt < 2; ++tt) {                                     \
            int gg = wave + 8 * tt;                                          \
            async_copy16(BT + (size_t)(bn + gg * 16 + srow) * KPAD           \
                             + (kt) + skc,                                   \
                         (dst) + gg * 512);                                  \
        } } while (0)

#define LOADAF(buf) do {                                                     \
        _Pragma("unroll")                                                    \
        for (int fb = 0; fb < 8; ++fb)                                       \
            af[fb] = *(const bf16x8*)((buf) + (wr * 8 + fb) * 512            \
                                      + lane * 8);                           \
    } while (0)

#define LOADBF(buf, half) do {                                               \
        _Pragma("unroll")                                                    \
        for (int jj = 0; jj < 2; ++jj)                                       \
            bfr[jj] = *(const bf16x8*)((buf) + (wc * 4 + (half) * 2 + jj)    \
                                       * 512 + lane * 8);                    \
    } while (0)

#define MFMA16(jb) do {                                                      \
        __builtin_amdgcn_s_setprio(1);                                       \
        _Pragma("unroll")                                                    \
        for (int fb = 0; fb < 8; ++fb) {                                     \
            acc[fb][(jb)]     = __builtin_amdgcn_mfma_f32_16x16x32_bf16(     \
                af[fb], bfr[0], acc[fb][(jb)], 0, 0, 0);                     \
            acc[fb][(jb) + 1] = __builtin_amdgcn_mfma_f32_16x16x32_bf16(     \
                af[fb], bfr[1], acc[fb][(jb) + 1], 0, 0, 0);                 \
        }                                                                    \
        __builtin_amdgcn_s_setprio(0);                                       \
    } while (0)

#define KSTEP(curA, curB, preA, preB, kt, dostage, endcnt) do {              \
        bf16x8 af[8], bfr[2];                                                \
        LOADAF(curA);                                                        \
        LOADBF(curB, 0);                                                     \
        if (dostage) STAGE_A2((kt), preA);                                   \
        BARX();                                                              \
        MFMA16(0);                                                           \
        BARX();                                                              \
        LOADBF(curB, 1);                                                     \
        if (dostage) STAGE_B2((kt), preB);                                   \
        BARX();                                                              \
        MFMA16(2);                                                           \
        asm volatile("s_waitcnt vmcnt(" #endcnt ")" ::: "memory");           \
        BARX();                                                              \
    } while (0)

    STAGE_A2(0, As0);  STAGE_B2(0, Bs0);
    STAGE_A2(32, As1); STAGE_B2(32, Bs1);
    asm volatile("s_waitcnt vmcnt(4)" ::: "memory");
    BARX();

    for (int m = 0; m < 36; m += 3) {
        KSTEP(As0, Bs0, As2, Bs2, (m + 2) * 32, 1, 4);   // u=m
        KSTEP(As1, Bs1, As0, Bs0, (m + 3) * 32, 1, 4);   // u=m+1
        KSTEP(As2, Bs2, As1, Bs1, (m + 4) * 32, 1, 4);   // u=m+2
    }
    KSTEP(As0, Bs0, As2, Bs2, 38 * 32, 1, 4);   // u=36: stage t38 -> slot2
    KSTEP(As1, Bs1, As0, Bs0, 39 * 32, 1, 4);   // u=37: stage t39 -> slot0
    KSTEP(As2, Bs2, As0, Bs0, 0,       0, 0);   // u=38: t38, drain t39
    KSTEP(As0, Bs0, As1, Bs1, 0,       0, 0);   // u=39: t39
#undef KSTEP
#undef MFMA16
#undef LOADBF
#undef LOADAF
#undef STAGE_B2
#undef STAGE_A2
#undef BARX

    const int seg = bn >> 10;   // 0,1,2 only (bn <= 2816)
#pragma unroll
    for (int i = 0; i < 8; ++i) {
#pragma unroll
        for (int r = 0; r < 4; ++r) {
            int gm = bm + wm + i * 16 + quad * 4 + r;
            if (gm >= N_NODES) continue;
#pragma unroll
            for (int j = 0; j < 4; ++j) {
                int gnl = (bn & 1023) + wn + j * 16 + l16;
                float v = acc[i][j][r];
                if (seg == 0)      fs0b[(size_t)gm * HD0 + gnl] = __float2bfloat16(v);
                else if (seg == 1) fd0b[(size_t)gm * HD0 + gnl] = __float2bfloat16(v);
                else               out0r[(size_t)gm * HD0 + gnl] = __float2bfloat16(v + b0f[gnl]);
            }
        }
    }
}

// merged layer-0 attention (blocks 0..9999) + gat_inner attention
// (blocks 10000..11249, 8 nodes each) -- one dispatch instead of two.
__global__ __launch_bounds__(256) void att0z_kernel(
        const int* __restrict__ rowptr, const int* __restrict__ csre,
        const int* __restrict__ src, const __hip_bfloat16* __restrict__ fs,
        const __hip_bfloat16* __restrict__ fd, const void* __restrict__ a0,
        const __hip_bfloat16* __restrict__ out0res, __hip_bfloat16* __restrict__ out0b,
        const float* __restrict__ z, const void* __restrict__ a2,
        float* __restrict__ h3, const int* __restrict__ dflag) {
    int f32 = *dflag;
    if (blockIdx.x >= N_NODES) {
        // ---- att32z path ----
        int n = (blockIdx.x - N_NODES) * 8 + (threadIdx.x >> 5);
        int lane = threadIdx.x & 31;
        int h = lane >> 3, o = lane & 7;
        float a2e = ldin(a2, h * 2 * D1 + o, f32);        // es half
        float a2d = ldin(a2, h * 2 * D1 + D1 + o, f32);   // ed half
        float zn = z[(size_t)n * HD1 + lane];
        float edn = zn * a2d;
        edn += __shfl_xor(edn, 1); edn += __shfl_xor(edn, 2); edn += __shfl_xor(edn, 4);
        float den = 0.f, acc = 0.f;
        int start = rowptr[n], end = rowptr[n + 1];
        for (int i = start; i < end; ++i) {
            int s = src[csre[i]];
            float zs = z[(size_t)s * HD1 + lane];
            float esv = zs * a2e;
            esv += __shfl_xor(esv, 1); esv += __shfl_xor(esv, 2); esv += __shfl_xor(esv, 4);
            float x = esv + edn;
            x = x > 0.f ? x : 0.2f * x;
            float p = expf(x);
            den += p;
            acc += p * zs;
        }
        h3[(size_t)n * HD1 + lane] = acc / fmaxf(den, 1e-9f);
        return;
    }
    // ---- att0 path ----
    int n = blockIdx.x;
    int t = threadIdx.x;
    __shared__ float sfd[HD0];
    __shared__ float sa0[HD0];
    __shared__ int sidx[128];
    int start = rowptr[n], end = rowptr[n + 1];
    int deg = end - start;
    {
        const unsigned short* fdp = (const unsigned short*)fd + (size_t)n * HD0;
        ushort4 u = *(const ushort4*)(fdp + 4 * t);
        sfd[4 * t + 0] = bfu2f(u.x); sfd[4 * t + 1] = bfu2f(u.y);
        sfd[4 * t + 2] = bfu2f(u.z); sfd[4 * t + 3] = bfu2f(u.w);
#pragma unroll
        for (int i = 0; i < 4; ++i) sa0[4 * t + i] = ldin(a0, 4 * t + i, f32);
        if (t < deg && t < 128) sidx[t] = src[csre[start + t]];
    }
    __syncthreads();
    const unsigned short* fsu = (const unsigned short*)fs;
    float den = 0.f;
    float acc[4] = {0.f, 0.f, 0.f, 0.f};
#pragma unroll 2
    for (int i = 0; i < deg; ++i) {
        int s = (i < 128) ? sidx[i] : src[csre[start + i]];
        ushort4 u = *(const ushort4*)(fsu + (size_t)s * HD0 + 4 * t);
        float fv[4], part = 0.f;
#pragma unroll
        for (int j = 0; j < 4; ++j) {
            unsigned short uj = (j == 0) ? u.x : (j == 1) ? u.y : (j == 2) ? u.z : u.w;
            fv[j] = bfu2f(uj);
            float x = fv[j] + sfd[4 * t + j];
            x = x > 0.f ? x : 0.2f * x;
            part += x * sa0[4 * t + j];
        }
        for (int off = 32; off > 0; off >>= 1) part += __shfl_xor(part, off);
        float p = expf(part);
        den += p;   // identical across the wave (= head)
#pragma unroll
        for (int j = 0; j < 4; ++j) acc[j] += p * fv[j];
    }
    float inv = 1.0f / fmaxf(den, 1e-9f);
    ushort4 ub = *(const ushort4*)((const unsigned short*)out0res + (size_t)n * HD0 + 4 * t);
    ushort4 o;
    o.x = f2bu(fmaxf(bfu2f(ub.x) + acc[0] * inv, 0.f));
    o.y = f2bu(fmaxf(bfu2f(ub.y) + acc[1] * inv, 0.f));
    o.z = f2bu(fmaxf(bfu2f(ub.z) + acc[2] * inv, 0.f));
    o.w = f2bu(fmaxf(bfu2f(ub.w) + acc[3] * inv, 0.f));
    *(ushort4*)((unsigned short*)out0b + (size_t)n * HD0 + 4 * t) = o;
}

// layer-1 fused MFMA GEMM, 2-way K-SPLIT: blocks [0,157) compute K 0..511,
// blocks [157,314) compute K 512..1023 into partial buffers (abf region, dead
// after the big GEMM).  att32e_final sums the partial pairs.
__global__ __launch_bounds__(256) void mfma_gemm96(
        const unsigned short* __restrict__ A, const unsigned short* __restrict__ BT1,
        const float* __restrict__ b1f, float* __restrict__ fs1,
        float* __restrict__ fd1, float* __restrict__ out1,
        float* __restrict__ fs1b, float* __restrict__ fd1b,
        float* __restrict__ out1b) {
    __shared__ unsigned short As0[2048], Bs0[3072], As1[2048], Bs1[3072];  // 20KB
    const int tid = threadIdx.x;
    const int wave = tid >> 6, lane = tid & 63;
    const int quad = lane >> 4, l16 = lane & 15;
    const int bk = blockIdx.x >= 157;           // K-half
    const int bm = (blockIdx.x - (bk ? 157 : 0)) * 64;
    const int kbase = bk ? 512 : 0;
    const int srow = lane & 15;
    const int skc  = (lane >> 4) * 8;
    const int NIT = 512 / 32;   // 16 (even)

    f32x4 acc[6];
#pragma unroll
    for (int j = 0; j < 6; ++j) acc[j] = (f32x4){0.f, 0.f, 0.f, 0.f};

#define STAGE96(kk, Adst, Bdst) do {                                              \
        async_copy16(A + (size_t)(bm + wave * 16 + srow) * HD0 + kbase + (kk) + skc, \
                     (Adst) + wave * 512);                                        \
        async_copy16(BT1 + (size_t)(wave * 16 + srow) * HD0 + kbase + (kk) + skc, \
                     (Bdst) + wave * 512);                                        \
        if (wave < 2)                                                             \
            async_copy16(BT1 + (size_t)((4 + wave) * 16 + srow) * HD0 + kbase + (kk) + skc, \
                         (Bdst) + (4 + wave) * 512);                              \
        } while (0)

#define COMPUTE96(Asrc, Bsrc) do {                                                \
        bf16x8 af = *(const bf16x8*)((Asrc) + wave * 512 + lane * 8);             \
        _Pragma("unroll")                                                         \
        for (int j = 0; j < 6; ++j) {                                             \
            bf16x8 bfr = *(const bf16x8*)((Bsrc) + j * 512 + lane * 8);           \
            acc[j] = __builtin_amdgcn_mfma_f32_16x16x32_bf16(af, bfr, acc[j], 0, 0, 0); \
        } } while (0)

    STAGE96(0, As0, Bs0);
    for (int it = 0; it < NIT; it += 2) {
        asm volatile("s_waitcnt vmcnt(0)" ::: "memory");
        asm volatile("s_barrier" ::: "memory");
        STAGE96((it + 1) * 32, As1, Bs1);
        COMPUTE96(As0, Bs0);
        asm volatile("s_waitcnt vmcnt(0)" ::: "memory");
        asm volatile("s_barrier" ::: "memory");
        if (it + 2 < NIT) STAGE96((it + 2) * 32, As0, Bs0);
        COMPUTE96(As1, Bs1);
    }
#undef STAGE96
#undef COMPUTE96

#pragma unroll
    for (int r = 0; r < 4; ++r) {
        int gm = bm + wave * 16 + quad * 4 + r;
        if (gm >= N_NODES) continue;
#pragma unroll
        for (int j = 0; j < 6; ++j) {
            int col = j * 16 + l16;
            int seg = col >> 5, cl = col & 31;
            float v = acc[j][r];
            if (!bk) {
                if (seg == 0)      fs1[(size_t)gm * HD1 + cl] = v;
                else if (seg == 1) fd1[(size_t)gm * HD1 + cl] = v;
                else               out1[(size_t)gm * HD1 + cl] = v + b1f[cl];
            } else {
                if (seg == 0)      fs1b[(size_t)gm * HD1 + cl] = v;
                else if (seg == 1) fd1b[(size_t)gm * HD1 + cl] = v;
                else               out1b[(size_t)gm * HD1 + cl] = v;
            }
        }
    }
}

// layer-1 attention + final linear fused, 8 nodes per 256-block.
// Sums the K-split partial pairs from mfma_gemm96.
__global__ __launch_bounds__(256) void att32e_final_kernel(
        const int* __restrict__ rowptr, const int* __restrict__ csre,
        const int* __restrict__ src, const float* __restrict__ fs1,
        const float* __restrict__ fd1, const void* __restrict__ a1,
        const float* __restrict__ out1g, const float* __restrict__ h3,
        const void* __restrict__ Wlin, const void* __restrict__ blin,
        void* __restrict__ out, const int* __restrict__ dflag,
        const float* __restrict__ fs1b, const float* __restrict__ fd1b,
        const float* __restrict__ out1gb) {
    int f32 = *dflag;
    int n = blockIdx.x * 8 + (threadIdx.x >> 5);
    int lane = threadIdx.x & 31;
    size_t ni = (size_t)n * HD1 + lane;
    float fdn = fd1[ni] + fd1b[ni];
    float a = ldin(a1, lane, f32);            // a1[h][o], lane = h*8+o
    float den = 0.f, acc = 0.f;
    int start = rowptr[n], end = rowptr[n + 1];
    for (int i = start; i < end; ++i) {
        int s = src[csre[i]];
        size_t si = (size_t)s * HD1 + lane;
        float fsv = fs1[si] + fs1b[si];
        float x = fsv + fdn;
        x = x > 0.f ? x : 0.2f * x;
        float term = x * a;
        term += __shfl_xor(term, 1);
        term += __shfl_xor(term, 2);
        term += __shfl_xor(term, 4);          // head-wide logit (8 lanes/oct)
        float p = expf(term);
        den += p;
        acc += p * fsv;
    }
    float out1v = fmaxf(out1g[ni] + out1gb[ni] + acc / fmaxf(den, 1e-9f), 0.f);
    float h3v = h3[ni];
    float partial[OUTF];
#pragma unroll
    for (int o = 0; o < OUTF; ++o)
        partial[o] = h3v * ldin(Wlin, (size_t)lane * OUTF + o, f32)
                   + out1v * ldin(Wlin, (size_t)(HD1 + lane) * OUTF + o, f32);
#pragma unroll
    for (int st = 1; st <= 16; st <<= 1)
#pragma unroll
        for (int o = 0; o < OUTF; ++o) partial[o] += __shfl_xor(partial[o], st);
    if (lane == 0) {
#pragma unroll
        for (int o = 0; o < OUTF; ++o) {
            float v = partial[o] + ldin(blin, o, f32);
            if (f32) ((float*)out)[(size_t)n * OUTF + o] = v;
            else     ((__hip_bfloat16*)out)[(size_t)n * OUTF + o] = __float2bfloat16(v);
        }
    }
}

// ---------------- launch ----------------
extern "C" void kernel_launch(void* const* d_in, const int* in_sizes, int n_in,
                              void* d_out, int out_size, void* d_ws, size_t ws_size,
                              hipStream_t stream) {
    const void* feats = d_in[0];
    const int*  src   = (const int*)d_in[1];
    const int*  dst   = (const int*)d_in[2];
    const void* tm    = d_in[3];
    const void* am    = d_in[4];
    const void* vm    = d_in[5];
    const void* W2    = d_in[6];
    const void* a2    = d_in[7];
    const void* Wl0   = d_in[8];
    const void* Wr0   = d_in[9];
    const void* a0    = d_in[10];
    const void* Wres0 = d_in[11];
    const void* b0    = d_in[12];
    const void* Wl1   = d_in[13];
    const void* Wr1   = d_in[14];
    const void* a1    = d_in[15];
    const void* Wres1 = d_in[16];
    const void* b1    = d_in[17];
    const void* Wlin  = d_in[18];
    const void* blin  = d_in[19];

    float* ws = (float*)d_ws;
    int*   dflag  = (int*)(ws + OFF_FLAG);
    float* colsum = ws + OFF_COLSUM;
    float* maskm  = ws + OFF_MASKM;
    float* z      = ws + OFF_Z;
    float* h3     = ws + OFF_H3;
    float* fs1    = ws + OFF_FS1;
    float* fd1    = ws + OFF_FD1;
    float* out1   = ws + OFF_OUT1;
    float* b0f    = ws + OFF_B0F;
    float* b1f    = ws + OFF_B1F;
    int*   deg    = (int*)(ws + OFF_DEG);
    int*   rowptr = (int*)(ws + OFF_ROWPTR);
    int*   cursor = (int*)(ws + OFF_CURSOR);
    int*   csre   = (int*)(ws + OFF_CSRE);
    __hip_bfloat16* out0r = (__hip_bfloat16*)(ws + OFF_OUT0);
    __hip_bfloat16* fs0b = (__hip_bfloat16*)(ws + OFF_FS0B);
    __hip_bfloat16* fd0b = (__hip_bfloat16*)(ws + OFF_FD0B);
    __hip_bfloat16* abf  = (__hip_bfloat16*)(ws + OFF_ABF);
    __hip_bfloat16* bt   = (__hip_bfloat16*)(ws + OFF_BT);
    __hip_bfloat16* bt1  = (__hip_bfloat16*)(ws + OFF_BT1);
    __hip_bfloat16* out0b = fd0b;   // fd0b row n retired after att0 block n reads it
    // K-split partials for gemm96 -- placed in the abf region (dead after the
    // big GEMM completes; gemm96 runs two dispatches later).
    float* fs1b  = ws + OFF_ABF;
    float* fd1b  = ws + OFF_ABF + 320000;
    float* out1b = ws + OFF_ABF + 640000;

    // single memset: dflag + colsum (contiguous). Other zeroing in init_kernel.
    (void)hipMemsetAsync(ws, 0, (16 + 1280) * sizeof(float), stream);

    // init: detect + deg-zero
    init_kernel<<<104, 256, 0, stream>>>((const unsigned short*)feats, dflag, deg);
    // colsum (500) + deg histogram (250) + small preps (5)
    prepA_kernel<<<755, 256, 0, stream>>>(feats, dst, tm, am, vm, b0, b1,
                                          colsum, deg, maskm, b0f, b1f, dflag);
    scan_kernel<<<1, 256, 0, stream>>>(deg, rowptr, cursor);
    scatter_kernel<<<(N_EDGES + 255) / 256, 256, 0, stream>>>(dst, cursor, csre);

    // big prep: A rows + z (fused) + weight transposes
    prepB_kernel<<<2560 + 3840 + 384, 256, 0, stream>>>(
        feats, colsum, maskm, abf, Wl0, Wr0, Wres0, W2, bt, Wl1, Wr1, Wres1,
        bt1, z, dflag);

    // big fused projection GEMM: clean 480-block grid, 2 occupancy rounds
    mfma_gemm<<<480, 512, 0, stream>>>(
        (const unsigned short*)abf, (const unsigned short*)bt, b0f, fs0b, fd0b, out0r);

    // GATv2 layer 0 attention + gat_inner attention (merged dispatch)
    att0z_kernel<<<N_NODES + N_NODES / 8, 256, 0, stream>>>(
        rowptr, csre, src, fs0b, fd0b, a0, out0r, out0b, z, a2, h3, dflag);

    // GATv2 layer 1 GEMM, 2-way K-split (314 blocks)
    mfma_gemm96<<<314, 256, 0, stream>>>(
        (const unsigned short*)out0b, (const unsigned short*)bt1, b1f,
        fs1, fd1, out1, fs1b, fd1b, out1b);

    // layer-1 attention + final linear fused (sums K-split partials)
    att32e_final_kernel<<<N_NODES / 8, 256, 0, stream>>>(
        rowptr, csre, src, fs1, fd1, a1, out1, h3, Wlin, blin, d_out, dflag,
        fs1b, fd1b, out1b);
}

// Round 13
// 447.095 us; speedup vs baseline: 1.3212x; 1.3212x over previous
//
#include <hip/hip_runtime.h>
#include <hip/hip_bf16.h>

// Problem constants
#define N_NODES 10000
#define N_EDGES 64000
#define IN_F    1247
#define KPAD    1280   // IN_F padded to mult of 32
#define NH      4
#define D0      256
#define D1      8
#define HD0     1024   // NH*D0
#define HD1     32     // NH*D1
#define NBIG    3072   // Wl0 | Wr0 | Wres0
#define OUTF    6
#define INV_N   (1.0f / 10000.0f)
#define MPAD    10240  // 40 row-tiles of 256

typedef __attribute__((ext_vector_type(8))) short bf16x8;
typedef __attribute__((ext_vector_type(4))) float f32x4;
typedef unsigned int u32;

// async 16B global -> LDS (DMA). LDS dest: wave-uniform base + lane*16.
__device__ __forceinline__ void async_copy16(const unsigned short* gsrc,
                                             unsigned short* ldst) {
    __builtin_amdgcn_global_load_lds(
        (const __attribute__((address_space(1))) u32*)(gsrc),
        (__attribute__((address_space(3))) u32*)(ldst), 16, 0, 0);
}

// ---------------- workspace layout (float-slot offsets) ----------------
constexpr size_t OFF_FLAG   = 0;                          // 16
constexpr size_t OFF_COLSUM = 16;                         // 1280
constexpr size_t OFF_MASKM  = 1296;                       // 1280
constexpr size_t OFF_Z      = 2576;                       // N*32
constexpr size_t OFF_H3     = OFF_Z    + 320000;          // N*32
constexpr size_t OFF_OUT0   = OFF_H3   + 320000;          // bf16 N*1024 (res+bias)
constexpr size_t OFF_FS1    = OFF_OUT0 + 10240000;        // N*32
constexpr size_t OFF_FD1    = OFF_FS1  + 320000;          // N*32
constexpr size_t OFF_OUT1   = OFF_FD1  + 320000;          // N*32
constexpr size_t OFF_B0F    = OFF_OUT1 + 320000;          // 1024
constexpr size_t OFF_B1F    = OFF_B0F  + 1024;            // 64
constexpr size_t OFF_DEG    = OFF_B1F  + 64;              // int 10016
constexpr size_t OFF_ROWPTR = OFF_DEG  + 10016;           // int 10016
constexpr size_t OFF_CURSOR = OFF_ROWPTR + 10016;         // int 10016
constexpr size_t OFF_CSRE   = OFF_CURSOR + 10016;         // int 64000
constexpr size_t OFF_FS0B   = OFF_CSRE + 64000;           // bf16 N*1024
constexpr size_t OFF_FD0B   = OFF_FS0B + 5120000;         // bf16 N*1024 (reused as out0b)
constexpr size_t OFF_ABF    = OFF_FD0B + 5120000;         // bf16 MPAD*KPAD (dead after big GEMM;
                                                          //  reused as fs1b/fd1b/out1b partials)
constexpr size_t OFF_BT     = OFF_ABF  + 6553600;         // bf16 3104*KPAD rows used
constexpr size_t OFF_BT1    = OFF_BT   + 2048000;         // bf16 96*1024
constexpr size_t WS_FLOATS  = OFF_BT1  + 49152;

// dual-dtype load: is_f32 ? float : bf16
__device__ __forceinline__ float ldin(const void* p, size_t i, int f32) {
    return f32 ? ((const float*)p)[i]
               : __bfloat162float(((const __hip_bfloat16*)p)[i]);
}
__device__ __forceinline__ float bfu2f(unsigned short u) {
    union { unsigned int i; float f; } x;
    x.i = ((unsigned int)u) << 16;
    return x.f;
}
__device__ __forceinline__ unsigned short f2bu(float v) {
    __hip_bfloat16 h = __float2bfloat16(v);
    unsigned short u;
    __builtin_memcpy(&u, &h, 2);
    return u;
}

// ---------------- kernels ----------------

// fused init: detect dtype (64 blocks) + zero deg (40)
__global__ void init_kernel(const unsigned short* __restrict__ feats_w,
                            int* __restrict__ flag, int* __restrict__ deg) {
    int b = blockIdx.x, t = threadIdx.x;
    if (b < 64) {
        int found = 0;
        for (int i = b * 256 + t; i < 131072; i += 64 * 256)
            if (((feats_w[i] >> 7) & 0xFF) == 0xFF) found = 1;
        if (found) atomicOr(flag, 1);
    } else {
        int idx = (b - 64) * 256 + t;
        if (idx < N_NODES + 16) deg[idx] = 0;
    }
}

// fused: colsum (500 blocks, 100 rows each) + deg histogram (250) + smallprep (5)
__global__ void prepA_kernel(const void* __restrict__ feats, const int* __restrict__ dst,
                             const void* __restrict__ tm, const void* __restrict__ am,
                             const void* __restrict__ vm, const void* __restrict__ b0,
                             const void* __restrict__ b1,
                             float* __restrict__ colsum, int* __restrict__ deg,
                             float* __restrict__ maskmul, float* __restrict__ b0f,
                             float* __restrict__ b1f, const int* __restrict__ dflag) {
    int b = blockIdx.x, t = threadIdx.x;
    if (b < 500) {
        int f32 = *dflag;
        int c = (b % 5) * 256 + t;
        if (c >= IN_F) return;
        int r0 = (b / 5) * 100;
        float s = 0.f;
        for (int r = r0; r < r0 + 100; ++r)
            s += ldin(feats, (size_t)r * IN_F + c, f32);
        atomicAdd(&colsum[c], s);
    } else if (b < 750) {
        int e = (b - 500) * 256 + t;
        if (e < N_EDGES) atomicAdd(&deg[dst[e]], 1);
    } else {
        int f32 = *dflag;
        int c = (b - 750) * 256 + t;
        if (c < IN_F) maskmul[c] = ldin(tm, c, f32) + ldin(am, c, f32) + ldin(vm, c, f32);
        if (c < HD0) b0f[c] = ldin(b0, c, f32);
        if (c < HD1) b1f[c] = ldin(b1, c, f32);
    }
}

// block-wide exclusive scan via wave shfl scan (no serial thread-0 loop)
__global__ __launch_bounds__(256) void scan_kernel(const int* __restrict__ deg,
                                                   int* __restrict__ rowptr,
                                                   int* __restrict__ cursor) {
    __shared__ int wtot[4];
    int t = threadIdx.x;
    int lane = t & 63, w = t >> 6;
    int base = t * 40;
    int s = 0;
    for (int i = 0; i < 40; ++i) {
        int idx = base + i;
        if (idx < N_NODES) s += deg[idx];
    }
    int inc = s;
#pragma unroll
    for (int d = 1; d < 64; d <<= 1) {
        int v = __shfl_up(inc, d);
        if (lane >= d) inc += v;
    }
    if (lane == 63) wtot[w] = inc;
    __syncthreads();
    int woff = 0;
    for (int ww = 0; ww < w; ++ww) woff += wtot[ww];
    int run = woff + inc - s;          // exclusive prefix for this thread
    for (int i = 0; i < 40; ++i) {
        int idx = base + i;
        if (idx < N_NODES) {
            rowptr[idx] = run; cursor[idx] = run;
            run += deg[idx];
        }
    }
    if (t == 255) rowptr[N_NODES] = woff + inc;   // grand total
}

__global__ void scatter_kernel(const int* __restrict__ dst, int* __restrict__ cursor,
                               int* __restrict__ csr_eid) {
    int e = blockIdx.x * 256 + threadIdx.x;
    if (e >= N_EDGES) return;
    int pos = atomicAdd(&cursor[dst[e]], 1);
    csr_eid[pos] = e;
}

// fused big prep (R10 form): prep_row wave-per-row (2560 blocks x 4 rows) +
// bt transpose (3840) + w2cols (160) + bt1 (384).  Z REMOVED from prepB --
// R12 measured the scalar z-loop at +150us (640 scalar 2B W2 loads/lane);
// z returns to the GEMM as tail-hidden strip blocks.
__global__ __launch_bounds__(256) void prepB_kernel(
        const void* __restrict__ feats, const float* __restrict__ colsum,
        const float* __restrict__ maskmul, __hip_bfloat16* __restrict__ abf,
        const void* __restrict__ Wl0, const void* __restrict__ Wr0,
        const void* __restrict__ Wres0, const void* __restrict__ W2,
        __hip_bfloat16* __restrict__ bt,
        const void* __restrict__ Wl1, const void* __restrict__ Wr1,
        const void* __restrict__ Wres1, __hip_bfloat16* __restrict__ bt1,
        const int* __restrict__ dflag) {
    __shared__ float smem[1056];
    int b = blockIdx.x, t = threadIdx.x;
    int f32 = *dflag;
    if (b < 2560) {
        int w = t >> 6, lane = t & 63;
        int n = b * 4 + w;
        unsigned short* arow = (unsigned short*)abf + (size_t)n * KPAD;
        if (n >= N_NODES) {
#pragma unroll
            for (int j = 0; j < 20; ++j) arow[j * 64 + lane] = 0;
            return;
        }
        float v[20];
        float s = 0.f;
#pragma unroll
        for (int j = 0; j < 20; ++j) {
            int c = j * 64 + lane;
            float f = (c < IN_F) ? ldin(feats, (size_t)n * IN_F + c, f32) : 0.f;
            float vv = (f != 0.0f) ? f
                     : ((c < IN_F) ? 0.5f * colsum[c] * INV_N : 0.f);  // 0.5*(h+h1)
            v[j] = vv;
            s += fabsf(vv);
        }
#pragma unroll
        for (int off = 32; off > 0; off >>= 1) s += __shfl_xor(s, off);
        float scale = 1.0f / fmaxf(s, 1e-12f);
#pragma unroll
        for (int j = 0; j < 20; ++j) {
            int c = j * 64 + lane;
            float vv = (c < IN_F) ? v[j] * scale * maskmul[c] : 0.f;
            arow[c] = f2bu(vv);
        }
    } else if (b < 2560 + 3840) {
        // LDS-tiled transpose of Wl0/Wr0/Wres0 -> bt rows 0..3071
        int b2 = b - 2560;
        int bz = b2 / 1280, rem = b2 - bz * 1280;
        int by = rem >> 5, bx = rem & 31;
        float (*tile)[33] = (float(*)[33])smem;
        int n0 = bx * 32, k0 = by * 32;
        const void* W = (bz == 0) ? Wl0 : (bz == 1) ? Wr0 : Wres0;
        int tx = t & 31, ty = t >> 5;
        for (int i = ty; i < 32; i += 8) {
            int k = k0 + i;
            tile[i][tx] = (k < IN_F) ? ldin(W, (size_t)k * HD0 + n0 + tx, f32) : 0.f;
        }
        __syncthreads();
        for (int i = ty; i < 32; i += 8)
            bt[(size_t)(bz * 1024 + n0 + i) * KPAD + k0 + tx] = __float2bfloat16(tile[tx][i]);
    } else if (b < 2560 + 3840 + 160) {
        // W2 z-columns -> bt rows 3072..3103 (coalesced over k)
        int idx = (b - (2560 + 3840)) * 256 + t;
        if (idx >= 32 * KPAD) return;
        int n = idx / KPAD, k = idx % KPAD;
        int hh = n >> 3, o = n & 7;
        float v = (k < IN_F) ? ldin(W2, ((size_t)hh * IN_F + k) * D1 + o, f32) : 0.f;
        bt[(size_t)(NBIG + n) * KPAD + k] = __float2bfloat16(v);
    } else {
        // bt1 [96][1024], coalesced writes
        int idx = (b - (2560 + 4000)) * 256 + t;
        if (idx >= 96 * HD0) return;
        int n = idx >> 10, k = idx & 1023;
        int seg = n >> 5, col = n & 31;
        const void* W = (seg == 0) ? Wl1 : (seg == 1) ? Wr1 : Wres1;
        bt1[idx] = __float2bfloat16(ldin(W, (size_t)k * HD1 + col, f32));
    }
}

// MFMA GEMM: C[MPAD x 3072] = abf @ bt^T (main) + z strip (bt rows 3072..3103).
// 512-BLOCK GRID = 480 main + 32 z-blocks: every CU gets exactly 2 blocks;
// z-blocks (indices 480..511) all land in dispatch round 2, so each CU runs
// [main,main]=2T or [main,z]=T+Tz (Tz~25-50 < T=62) -> wall = 2T ~ 124us with
// z FULLY hidden.  (R10's 520 grid had an 8-z-block round 3 = +20us tail;
// R12's z-in-prepB was +150us of scalar loads.)  z-block: 320 rows x 32 cols,
// 8 waves x 40 rows via 3 overlapping row-frags (duplicate rows write
// identical values; reads clamped to zeroed pad row 10239).
// Main path byte-identical to R8/R10 best: fine-interleave + counted
// vmcnt(4), 3-slot BK=32, 8 waves, XCD swizzle.
__global__ __launch_bounds__(512) void mfma_gemm(
        const unsigned short* __restrict__ A, const unsigned short* __restrict__ BT,
        const float* __restrict__ b0f, __hip_bfloat16* __restrict__ fs0b,
        __hip_bfloat16* __restrict__ fd0b, __hip_bfloat16* __restrict__ out0r,
        float* __restrict__ z) {
    __shared__ unsigned short As0[8192], Bs0[8192];   // slot 0 (16KB + 16KB)
    __shared__ unsigned short As1[8192], Bs1[8192];   // slot 1
    __shared__ unsigned short As2[8192], Bs2[8192];   // slot 2  (96KB)
    const int g = blockIdx.x;
    const int tid = threadIdx.x;
    const int wave = tid >> 6, lane = tid & 63;
    const int quad = lane >> 4, l16 = lane & 15;
    const int srow = lane & 15;
    const int skc  = (lane >> 4) * 8;

    if (g >= 480) {
        // ---- z strip: 320 rows x 32 cols (BT rows 3072..3103), K=1280 ----
        // register-only pipeline: 5 bf16x8 loads + 6 MFMAs per k-step.
        int zb = g - 480;                                  // [0,32)
        int rbase = zb * 320 + wave * 40;                  // 8 waves x 40 rows
        int r0 = rbase + srow;
        int r1 = rbase + 16 + srow;
        int r2 = rbase + 32 + srow;
        r2 = r2 < MPAD ? r2 : (MPAD - 1);                  // clamp to zeroed pad
        const unsigned short* B0p = BT + (size_t)(NBIG + srow) * KPAD;
        const unsigned short* B1p = BT + (size_t)(NBIG + 16 + srow) * KPAD;
        f32x4 zacc[3][2];
#pragma unroll
        for (int i = 0; i < 3; ++i)
#pragma unroll
            for (int j = 0; j < 2; ++j) zacc[i][j] = (f32x4){0.f, 0.f, 0.f, 0.f};
#pragma unroll 2
        for (int kk = 0; kk < KPAD; kk += 32) {
            bf16x8 a0 = *(const bf16x8*)(A + (size_t)r0 * KPAD + kk + skc);
            bf16x8 a1 = *(const bf16x8*)(A + (size_t)r1 * KPAD + kk + skc);
            bf16x8 a2 = *(const bf16x8*)(A + (size_t)r2 * KPAD + kk + skc);
            bf16x8 b0 = *(const bf16x8*)(B0p + kk + skc);
            bf16x8 b1 = *(const bf16x8*)(B1p + kk + skc);
            zacc[0][0] = __builtin_amdgcn_mfma_f32_16x16x32_bf16(a0, b0, zacc[0][0], 0, 0, 0);
            zacc[0][1] = __builtin_amdgcn_mfma_f32_16x16x32_bf16(a0, b1, zacc[0][1], 0, 0, 0);
            zacc[1][0] = __builtin_amdgcn_mfma_f32_16x16x32_bf16(a1, b0, zacc[1][0], 0, 0, 0);
            zacc[1][1] = __builtin_amdgcn_mfma_f32_16x16x32_bf16(a1, b1, zacc[1][1], 0, 0, 0);
            zacc[2][0] = __builtin_amdgcn_mfma_f32_16x16x32_bf16(a2, b0, zacc[2][0], 0, 0, 0);
            zacc[2][1] = __builtin_amdgcn_mfma_f32_16x16x32_bf16(a2, b1, zacc[2][1], 0, 0, 0);
        }
#pragma unroll
        for (int rf = 0; rf < 3; ++rf)
#pragma unroll
            for (int r = 0; r < 4; ++r) {
                int gm = rbase + rf * 16 + quad * 4 + r;
                if (gm >= N_NODES) continue;
#pragma unroll
                for (int cf = 0; cf < 2; ++cf)
                    z[(size_t)gm * HD1 + cf * 16 + l16] = zacc[rf][cf][r];
            }
        return;
    }

    // ---- main path: 480 blocks = 8 XCD x 60 (5 row x 12 col) ----
    const int xcd = g & 7, l = g >> 3;          // l in [0,60)
    const int colt = l / 5, rowi = l - colt * 5;
    const int bm = (xcd * 5 + rowi) * 256;
    const int bn = colt * 256;
    const int wr = wave >> 2, wc = wave & 3;    // 2 x 4 wave grid
    const int wm = wr * 128, wn = wc * 64;

    f32x4 acc[8][4];
#pragma unroll
    for (int i = 0; i < 8; ++i)
#pragma unroll
        for (int j = 0; j < 4; ++j) acc[i][j] = (f32x4){0.f, 0.f, 0.f, 0.f};

#define BARX() do { __builtin_amdgcn_s_barrier();                            \
                    __builtin_amdgcn_sched_barrier(0); } while (0)

#define STAGE_A2(kt, dst) do {                                               \
        _Pragma("unroll")                                                    \
        for (int tt = 0; tt < 2; ++tt) {                                     \
            int gg = wave + 8 * tt;                                          \
            async_copy16(A + (size_t)(bm + gg * 16 + srow) * KPAD            \
                             + (kt) + skc,                                   \
                         (dst) + gg * 512);                                  \
        } } while (0)

#define STAGE_B2(kt, dst) do {                                               \
        _Pragma("unroll")                                                    \
        for (int tt = 0; tt < 2; ++tt) {                                     \
            int gg = wave + 8 * tt;                                          \
            async_copy16(BT + (size_t)(bn + gg * 16 + srow) * KPAD           \
                             + (kt) + skc,                                   \
                         (dst) + gg * 512);                                  \
        } } while (0)

#define LOADAF(buf) do {                                                     \
        _Pragma("unroll")                                                    \
        for (int fb = 0; fb < 8; ++fb)                                       \
            af[fb] = *(const bf16x8*)((buf) + (wr * 8 + fb) * 512            \
                                      + lane * 8);                           \
    } while (0)

#define LOADBF(buf, half) do {                                               \
        _Pragma("unroll")                                                    \
        for (int jj = 0; jj < 2; ++jj)                                       \
            bfr[jj] = *(const bf16x8*)((buf) + (wc * 4 + (half) * 2 + jj)    \
                                       * 512 + lane * 8);                    \
    } while (0)

#define MFMA16(jb) do {                                                      \
        __builtin_amdgcn_s_setprio(1);                                       \
        _Pragma("unroll")                                                    \
        for (int fb = 0; fb < 8; ++fb) {                                     \
            acc[fb][(jb)]     = __builtin_amdgcn_mfma_f32_16x16x32_bf16(     \
                af[fb], bfr[0], acc[fb][(jb)], 0, 0, 0);                     \
            acc[fb][(jb) + 1] = __builtin_amdgcn_mfma_f32_16x16x32_bf16(     \
                af[fb], bfr[1], acc[fb][(jb) + 1], 0, 0, 0);                 \
        }                                                                    \
        __builtin_amdgcn_s_setprio(0);                                       \
    } while (0)

#define KSTEP(curA, curB, preA, preB, kt, dostage, endcnt) do {              \
        bf16x8 af[8], bfr[2];                                                \
        LOADAF(curA);                                                        \
        LOADBF(curB, 0);                                                     \
        if (dostage) STAGE_A2((kt), preA);                                   \
        BARX();                                                              \
        MFMA16(0);                                                           \
        BARX();                                                              \
        LOADBF(curB, 1);                                                     \
        if (dostage) STAGE_B2((kt), preB);                                   \
        BARX();                                                              \
        MFMA16(2);                                                           \
        asm volatile("s_waitcnt vmcnt(" #endcnt ")" ::: "memory");           \
        BARX();                                                              \
    } while (0)

    STAGE_A2(0, As0);  STAGE_B2(0, Bs0);
    STAGE_A2(32, As1); STAGE_B2(32, Bs1);
    asm volatile("s_waitcnt vmcnt(4)" ::: "memory");
    BARX();

    for (int m = 0; m < 36; m += 3) {
        KSTEP(As0, Bs0, As2, Bs2, (m + 2) * 32, 1, 4);   // u=m
        KSTEP(As1, Bs1, As0, Bs0, (m + 3) * 32, 1, 4);   // u=m+1
        KSTEP(As2, Bs2, As1, Bs1, (m + 4) * 32, 1, 4);   // u=m+2
    }
    KSTEP(As0, Bs0, As2, Bs2, 38 * 32, 1, 4);   // u=36: stage t38 -> slot2
    KSTEP(As1, Bs1, As0, Bs0, 39 * 32, 1, 4);   // u=37: stage t39 -> slot0
    KSTEP(As2, Bs2, As0, Bs0, 0,       0, 0);   // u=38: t38, drain t39
    KSTEP(As0, Bs0, As1, Bs1, 0,       0, 0);   // u=39: t39
#undef KSTEP
#undef MFMA16
#undef LOADBF
#undef LOADAF
#undef STAGE_B2
#undef STAGE_A2
#undef BARX

    const int seg = bn >> 10;   // 0,1,2 only (bn <= 2816)
#pragma unroll
    for (int i = 0; i < 8; ++i) {
#pragma unroll
        for (int r = 0; r < 4; ++r) {
            int gm = bm + wm + i * 16 + quad * 4 + r;
            if (gm >= N_NODES) continue;
#pragma unroll
            for (int j = 0; j < 4; ++j) {
                int gnl = (bn & 1023) + wn + j * 16 + l16;
                float v = acc[i][j][r];
                if (seg == 0)      fs0b[(size_t)gm * HD0 + gnl] = __float2bfloat16(v);
                else if (seg == 1) fd0b[(size_t)gm * HD0 + gnl] = __float2bfloat16(v);
                else               out0r[(size_t)gm * HD0 + gnl] = __float2bfloat16(v + b0f[gnl]);
            }
        }
    }
}

// merged layer-0 attention (blocks 0..9999) + gat_inner attention
// (blocks 10000..11249, 8 nodes each) -- one dispatch instead of two.
__global__ __launch_bounds__(256) void att0z_kernel(
        const int* __restrict__ rowptr, const int* __restrict__ csre,
        const int* __restrict__ src, const __hip_bfloat16* __restrict__ fs,
        const __hip_bfloat16* __restrict__ fd, const void* __restrict__ a0,
        const __hip_bfloat16* __restrict__ out0res, __hip_bfloat16* __restrict__ out0b,
        const float* __restrict__ z, const void* __restrict__ a2,
        float* __restrict__ h3, const int* __restrict__ dflag) {
    int f32 = *dflag;
    if (blockIdx.x >= N_NODES) {
        // ---- att32z path ----
        int n = (blockIdx.x - N_NODES) * 8 + (threadIdx.x >> 5);
        int lane = threadIdx.x & 31;
        int h = lane >> 3, o = lane & 7;
        float a2e = ldin(a2, h * 2 * D1 + o, f32);        // es half
        float a2d = ldin(a2, h * 2 * D1 + D1 + o, f32);   // ed half
        float zn = z[(size_t)n * HD1 + lane];
        float edn = zn * a2d;
        edn += __shfl_xor(edn, 1); edn += __shfl_xor(edn, 2); edn += __shfl_xor(edn, 4);
        float den = 0.f, acc = 0.f;
        int start = rowptr[n], end = rowptr[n + 1];
        for (int i = start; i < end; ++i) {
            int s = src[csre[i]];
            float zs = z[(size_t)s * HD1 + lane];
            float esv = zs * a2e;
            esv += __shfl_xor(esv, 1); esv += __shfl_xor(esv, 2); esv += __shfl_xor(esv, 4);
            float x = esv + edn;
            x = x > 0.f ? x : 0.2f * x;
            float p = expf(x);
            den += p;
            acc += p * zs;
        }
        h3[(size_t)n * HD1 + lane] = acc / fmaxf(den, 1e-9f);
        return;
    }
    // ---- att0 path ----
    int n = blockIdx.x;
    int t = threadIdx.x;
    __shared__ float sfd[HD0];
    __shared__ float sa0[HD0];
    __shared__ int sidx[128];
    int start = rowptr[n], end = rowptr[n + 1];
    int deg = end - start;
    {
        const unsigned short* fdp = (const unsigned short*)fd + (size_t)n * HD0;
        ushort4 u = *(const ushort4*)(fdp + 4 * t);
        sfd[4 * t + 0] = bfu2f(u.x); sfd[4 * t + 1] = bfu2f(u.y);
        sfd[4 * t + 2] = bfu2f(u.z); sfd[4 * t + 3] = bfu2f(u.w);
#pragma unroll
        for (int i = 0; i < 4; ++i) sa0[4 * t + i] = ldin(a0, 4 * t + i, f32);
        if (t < deg && t < 128) sidx[t] = src[csre[start + t]];
    }
    __syncthreads();
    const unsigned short* fsu = (const unsigned short*)fs;
    float den = 0.f;
    float acc[4] = {0.f, 0.f, 0.f, 0.f};
#pragma unroll 2
    for (int i = 0; i < deg; ++i) {
        int s = (i < 128) ? sidx[i] : src[csre[start + i]];
        ushort4 u = *(const ushort4*)(fsu + (size_t)s * HD0 + 4 * t);
        float fv[4], part = 0.f;
#pragma unroll
        for (int j = 0; j < 4; ++j) {
            unsigned short uj = (j == 0) ? u.x : (j == 1) ? u.y : (j == 2) ? u.z : u.w;
            fv[j] = bfu2f(uj);
            float x = fv[j] + sfd[4 * t + j];
            x = x > 0.f ? x : 0.2f * x;
            part += x * sa0[4 * t + j];
        }
        for (int off = 32; off > 0; off >>= 1) part += __shfl_xor(part, off);
        float p = expf(part);
        den += p;   // identical across the wave (= head)
#pragma unroll
        for (int j = 0; j < 4; ++j) acc[j] += p * fv[j];
    }
    float inv = 1.0f / fmaxf(den, 1e-9f);
    ushort4 ub = *(const ushort4*)((const unsigned short*)out0res + (size_t)n * HD0 + 4 * t);
    ushort4 o;
    o.x = f2bu(fmaxf(bfu2f(ub.x) + acc[0] * inv, 0.f));
    o.y = f2bu(fmaxf(bfu2f(ub.y) + acc[1] * inv, 0.f));
    o.z = f2bu(fmaxf(bfu2f(ub.z) + acc[2] * inv, 0.f));
    o.w = f2bu(fmaxf(bfu2f(ub.w) + acc[3] * inv, 0.f));
    *(ushort4*)((unsigned short*)out0b + (size_t)n * HD0 + 4 * t) = o;
}

// layer-1 fused MFMA GEMM, 2-way K-SPLIT: blocks [0,157) compute K 0..511,
// blocks [157,314) compute K 512..1023 into partial buffers (abf region, dead
// after the big GEMM).  att32e_final sums the partial pairs.
__global__ __launch_bounds__(256) void mfma_gemm96(
        const unsigned short* __restrict__ A, const unsigned short* __restrict__ BT1,
        const float* __restrict__ b1f, float* __restrict__ fs1,
        float* __restrict__ fd1, float* __restrict__ out1,
        float* __restrict__ fs1b, float* __restrict__ fd1b,
        float* __restrict__ out1b) {
    __shared__ unsigned short As0[2048], Bs0[3072], As1[2048], Bs1[3072];  // 20KB
    const int tid = threadIdx.x;
    const int wave = tid >> 6, lane = tid & 63;
    const int quad = lane >> 4, l16 = lane & 15;
    const int bk = blockIdx.x >= 157;           // K-half
    const int bm = (blockIdx.x - (bk ? 157 : 0)) * 64;
    const int kbase = bk ? 512 : 0;
    const int srow = lane & 15;
    const int skc  = (lane >> 4) * 8;
    const int NIT = 512 / 32;   // 16 (even)

    f32x4 acc[6];
#pragma unroll
    for (int j = 0; j < 6; ++j) acc[j] = (f32x4){0.f, 0.f, 0.f, 0.f};

#define STAGE96(kk, Adst, Bdst) do {                                              \
        async_copy16(A + (size_t)(bm + wave * 16 + srow) * HD0 + kbase + (kk) + skc, \
                     (Adst) + wave * 512);                                        \
        async_copy16(BT1 + (size_t)(wave * 16 + srow) * HD0 + kbase + (kk) + skc, \
                     (Bdst) + wave * 512);                                        \
        if (wave < 2)                                                             \
            async_copy16(BT1 + (size_t)((4 + wave) * 16 + srow) * HD0 + kbase + (kk) + skc, \
                         (Bdst) + (4 + wave) * 512);                              \
        } while (0)

#define COMPUTE96(Asrc, Bsrc) do {                                                \
        bf16x8 af = *(const bf16x8*)((Asrc) + wave * 512 + lane * 8);             \
        _Pragma("unroll")                                                         \
        for (int j = 0; j < 6; ++j) {                                             \
            bf16x8 bfr = *(const bf16x8*)((Bsrc) + j * 512 + lane * 8);           \
            acc[j] = __builtin_amdgcn_mfma_f32_16x16x32_bf16(af, bfr, acc[j], 0, 0, 0); \
        } } while (0)

    STAGE96(0, As0, Bs0);
    for (int it = 0; it < NIT; it += 2) {
        asm volatile("s_waitcnt vmcnt(0)" ::: "memory");
        asm volatile("s_barrier" ::: "memory");
        STAGE96((it + 1) * 32, As1, Bs1);
        COMPUTE96(As0, Bs0);
        asm volatile("s_waitcnt vmcnt(0)" ::: "memory");
        asm volatile("s_barrier" ::: "memory");
        if (it + 2 < NIT) STAGE96((it + 2) * 32, As0, Bs0);
        COMPUTE96(As1, Bs1);
    }
#undef STAGE96
#undef COMPUTE96

#pragma unroll
    for (int r = 0; r < 4; ++r) {
        int gm = bm + wave * 16 + quad * 4 + r;
        if (gm >= N_NODES) continue;
#pragma unroll
        for (int j = 0; j < 6; ++j) {
            int col = j * 16 + l16;
            int seg = col >> 5, cl = col & 31;
            float v = acc[j][r];
            if (!bk) {
                if (seg == 0)      fs1[(size_t)gm * HD1 + cl] = v;
                else if (seg == 1) fd1[(size_t)gm * HD1 + cl] = v;
                else               out1[(size_t)gm * HD1 + cl] = v + b1f[cl];
            } else {
                if (seg == 0)      fs1b[(size_t)gm * HD1 + cl] = v;
                else if (seg == 1) fd1b[(size_t)gm * HD1 + cl] = v;
                else               out1b[(size_t)gm * HD1 + cl] = v;
            }
        }
    }
}

// layer-1 attention + final linear fused, 8 nodes per 256-block.
// Sums the K-split partial pairs from mfma_gemm96.
__global__ __launch_bounds__(256) void att32e_final_kernel(
        const int* __restrict__ rowptr, const int* __restrict__ csre,
        const int* __restrict__ src, const float* __restrict__ fs1,
        const float* __restrict__ fd1, const void* __restrict__ a1,
        const float* __restrict__ out1g, const float* __restrict__ h3,
        const void* __restrict__ Wlin, const void* __restrict__ blin,
        void* __restrict__ out, const int* __restrict__ dflag,
        const float* __restrict__ fs1b, const float* __restrict__ fd1b,
        const float* __restrict__ out1gb) {
    int f32 = *dflag;
    int n = blockIdx.x * 8 + (threadIdx.x >> 5);
    int lane = threadIdx.x & 31;
    size_t ni = (size_t)n * HD1 + lane;
    float fdn = fd1[ni] + fd1b[ni];
    float a = ldin(a1, lane, f32);            // a1[h][o], lane = h*8+o
    float den = 0.f, acc = 0.f;
    int start = rowptr[n], end = rowptr[n + 1];
    for (int i = start; i < end; ++i) {
        int s = src[csre[i]];
        size_t si = (size_t)s * HD1 + lane;
        float fsv = fs1[si] + fs1b[si];
        float x = fsv + fdn;
        x = x > 0.f ? x : 0.2f * x;
        float term = x * a;
        term += __shfl_xor(term, 1);
        term += __shfl_xor(term, 2);
        term += __shfl_xor(term, 4);          // head-wide logit (8 lanes/oct)
        float p = expf(term);
        den += p;
        acc += p * fsv;
    }
    float out1v = fmaxf(out1g[ni] + out1gb[ni] + acc / fmaxf(den, 1e-9f), 0.f);
    float h3v = h3[ni];
    float partial[OUTF];
#pragma unroll
    for (int o = 0; o < OUTF; ++o)
        partial[o] = h3v * ldin(Wlin, (size_t)lane * OUTF + o, f32)
                   + out1v * ldin(Wlin, (size_t)(HD1 + lane) * OUTF + o, f32);
#pragma unroll
    for (int st = 1; st <= 16; st <<= 1)
#pragma unroll
        for (int o = 0; o < OUTF; ++o) partial[o] += __shfl_xor(partial[o], st);
    if (lane == 0) {
#pragma unroll
        for (int o = 0; o < OUTF; ++o) {
            float v = partial[o] + ldin(blin, o, f32);
            if (f32) ((float*)out)[(size_t)n * OUTF + o] = v;
            else     ((__hip_bfloat16*)out)[(size_t)n * OUTF + o] = __float2bfloat16(v);
        }
    }
}

// ---------------- launch ----------------
extern "C" void kernel_launch(void* const* d_in, const int* in_sizes, int n_in,
                              void* d_out, int out_size, void* d_ws, size_t ws_size,
                              hipStream_t stream) {
    const void* feats = d_in[0];
    const int*  src   = (const int*)d_in[1];
    const int*  dst   = (const int*)d_in[2];
    const void* tm    = d_in[3];
    const void* am    = d_in[4];
    const void* vm    = d_in[5];
    const void* W2    = d_in[6];
    const void* a2    = d_in[7];
    const void* Wl0   = d_in[8];
    const void* Wr0   = d_in[9];
    const void* a0    = d_in[10];
    const void* Wres0 = d_in[11];
    const void* b0    = d_in[12];
    const void* Wl1   = d_in[13];
    const void* Wr1   = d_in[14];
    const void* a1    = d_in[15];
    const void* Wres1 = d_in[16];
    const void* b1    = d_in[17];
    const void* Wlin  = d_in[18];
    const void* blin  = d_in[19];

    float* ws = (float*)d_ws;
    int*   dflag  = (int*)(ws + OFF_FLAG);
    float* colsum = ws + OFF_COLSUM;
    float* maskm  = ws + OFF_MASKM;
    float* z      = ws + OFF_Z;
    float* h3     = ws + OFF_H3;
    float* fs1    = ws + OFF_FS1;
    float* fd1    = ws + OFF_FD1;
    float* out1   = ws + OFF_OUT1;
    float* b0f    = ws + OFF_B0F;
    float* b1f    = ws + OFF_B1F;
    int*   deg    = (int*)(ws + OFF_DEG);
    int*   rowptr = (int*)(ws + OFF_ROWPTR);
    int*   cursor = (int*)(ws + OFF_CURSOR);
    int*   csre   = (int*)(ws + OFF_CSRE);
    __hip_bfloat16* out0r = (__hip_bfloat16*)(ws + OFF_OUT0);
    __hip_bfloat16* fs0b = (__hip_bfloat16*)(ws + OFF_FS0B);
    __hip_bfloat16* fd0b = (__hip_bfloat16*)(ws + OFF_FD0B);
    __hip_bfloat16* abf  = (__hip_bfloat16*)(ws + OFF_ABF);
    __hip_bfloat16* bt   = (__hip_bfloat16*)(ws + OFF_BT);
    __hip_bfloat16* bt1  = (__hip_bfloat16*)(ws + OFF_BT1);
    __hip_bfloat16* out0b = fd0b;   // fd0b row n retired after att0 block n reads it
    // K-split partials for gemm96 -- placed in the abf region (dead after the
    // big GEMM completes; gemm96 runs two dispatches later).
    float* fs1b  = ws + OFF_ABF;
    float* fd1b  = ws + OFF_ABF + 320000;
    float* out1b = ws + OFF_ABF + 640000;

    // single memset: dflag + colsum (contiguous). Other zeroing in init_kernel.
    (void)hipMemsetAsync(ws, 0, (16 + 1280) * sizeof(float), stream);

    // init: detect + deg-zero
    init_kernel<<<104, 256, 0, stream>>>((const unsigned short*)feats, dflag, deg);
    // colsum (500) + deg histogram (250) + small preps (5)
    prepA_kernel<<<755, 256, 0, stream>>>(feats, dst, tm, am, vm, b0, b1,
                                          colsum, deg, maskm, b0f, b1f, dflag);
    scan_kernel<<<1, 256, 0, stream>>>(deg, rowptr, cursor);
    scatter_kernel<<<(N_EDGES + 255) / 256, 256, 0, stream>>>(dst, cursor, csre);

    // big prep: A rows (wave-per-row) + weight transposes + w2cols
    prepB_kernel<<<2560 + 3840 + 160 + 384, 256, 0, stream>>>(
        feats, colsum, maskm, abf, Wl0, Wr0, Wres0, W2, bt, Wl1, Wr1, Wres1,
        bt1, dflag);

    // big fused projection GEMM: 480 main + 32 z-strip blocks = 512 = exactly
    // 2 occupancy rounds; z fully hidden in round-2 slack
    mfma_gemm<<<512, 512, 0, stream>>>(
        (const unsigned short*)abf, (const unsigned short*)bt, b0f, fs0b, fd0b,
        out0r, z);

    // GATv2 layer 0 attention + gat_inner attention (merged dispatch)
    att0z_kernel<<<N_NODES + N_NODES / 8, 256, 0, stream>>>(
        rowptr, csre, src, fs0b, fd0b, a0, out0r, out0b, z, a2, h3, dflag);

    // GATv2 layer 1 GEMM, 2-way K-split (314 blocks)
    mfma_gemm96<<<314, 256, 0, stream>>>(
        (const unsigned short*)out0b, (const unsigned short*)bt1, b1f,
        fs1, fd1, out1, fs1b, fd1b, out1b);

    // layer-1 attention + final linear fused (sums K-split partials)
    att32e_final_kernel<<<N_NODES / 8, 256, 0, stream>>>(
        rowptr, csre, src, fs1, fd1, a1, out1, h3, Wlin, blin, d_out, dflag,
        fs1b, fd1b, out1b);
}

// Round 14
// 438.925 us; speedup vs baseline: 1.3458x; 1.0186x over previous
//
#include <hip/hip_runtime.h>
#include <hip/hip_bf16.h>

// Problem constants
#define N_NODES 10000
#define N_EDGES 64000
#define IN_F    1247
#define KPAD    1280   // IN_F padded to mult of 32
#define NH      4
#define D0      256
#define D1      8
#define HD0     1024   // NH*D0
#define HD1     32     // NH*D1
#define NBIG    3072   // Wl0 | Wr0 | Wres0
#define OUTF    6
#define INV_N   (1.0f / 10000.0f)
#define MPAD    10240  // 40 row-tiles of 256

typedef __attribute__((ext_vector_type(8))) short bf16x8;
typedef __attribute__((ext_vector_type(4))) float f32x4;
typedef unsigned int u32;

// async 16B global -> LDS (DMA). LDS dest: wave-uniform base + lane*16.
__device__ __forceinline__ void async_copy16(const unsigned short* gsrc,
                                             unsigned short* ldst) {
    __builtin_amdgcn_global_load_lds(
        (const __attribute__((address_space(1))) u32*)(gsrc),
        (__attribute__((address_space(3))) u32*)(ldst), 16, 0, 0);
}

// ---------------- workspace layout (float-slot offsets) ----------------
constexpr size_t OFF_FLAG   = 0;                          // 16
constexpr size_t OFF_COLSUM = 16;                         // 1280
constexpr size_t OFF_MASKM  = 1296;                       // 1280
constexpr size_t OFF_Z      = 2576;                       // N*32
constexpr size_t OFF_H3     = OFF_Z    + 320000;          // N*32
constexpr size_t OFF_OUT0   = OFF_H3   + 320000;          // bf16 N*1024 (res+bias)
constexpr size_t OFF_FS1    = OFF_OUT0 + 10240000;        // N*32
constexpr size_t OFF_FD1    = OFF_FS1  + 320000;          // N*32
constexpr size_t OFF_OUT1   = OFF_FD1  + 320000;          // N*32
constexpr size_t OFF_B0F    = OFF_OUT1 + 320000;          // 1024
constexpr size_t OFF_B1F    = OFF_B0F  + 1024;            // 64
constexpr size_t OFF_DEG    = OFF_B1F  + 64;              // int 10016
constexpr size_t OFF_ROWPTR = OFF_DEG  + 10016;           // int 10016
constexpr size_t OFF_CURSOR = OFF_ROWPTR + 10016;         // int 10016
constexpr size_t OFF_CSRE   = OFF_CURSOR + 10016;         // int 64000
constexpr size_t OFF_FS0B   = OFF_CSRE + 64000;           // bf16 N*1024
constexpr size_t OFF_FD0B   = OFF_FS0B + 5120000;         // bf16 N*1024 (reused as out0b)
constexpr size_t OFF_ABF    = OFF_FD0B + 5120000;         // bf16 MPAD*KPAD (dead after big GEMM;
                                                          //  reused as fs1b/fd1b/out1b partials)
constexpr size_t OFF_BT     = OFF_ABF  + 6553600;         // bf16 3104*KPAD rows used
constexpr size_t OFF_BT1    = OFF_BT   + 2048000;         // bf16 96*1024
constexpr size_t WS_FLOATS  = OFF_BT1  + 49152;

// dual-dtype load: is_f32 ? float : bf16
__device__ __forceinline__ float ldin(const void* p, size_t i, int f32) {
    return f32 ? ((const float*)p)[i]
               : __bfloat162float(((const __hip_bfloat16*)p)[i]);
}
__device__ __forceinline__ float bfu2f(unsigned short u) {
    union { unsigned int i; float f; } x;
    x.i = ((unsigned int)u) << 16;
    return x.f;
}
__device__ __forceinline__ unsigned short f2bu(float v) {
    __hip_bfloat16 h = __float2bfloat16(v);
    unsigned short u;
    __builtin_memcpy(&u, &h, 2);
    return u;
}

// ---------------- kernels ----------------

// fused init: detect dtype (64 blocks) + zero deg (40)
__global__ void init_kernel(const unsigned short* __restrict__ feats_w,
                            int* __restrict__ flag, int* __restrict__ deg) {
    int b = blockIdx.x, t = threadIdx.x;
    if (b < 64) {
        int found = 0;
        for (int i = b * 256 + t; i < 131072; i += 64 * 256)
            if (((feats_w[i] >> 7) & 0xFF) == 0xFF) found = 1;
        if (found) atomicOr(flag, 1);
    } else {
        int idx = (b - 64) * 256 + t;
        if (idx < N_NODES + 16) deg[idx] = 0;
    }
}

// fused: colsum (500 blocks, 100 rows each) + deg histogram (250) + smallprep (5)
__global__ void prepA_kernel(const void* __restrict__ feats, const int* __restrict__ dst,
                             const void* __restrict__ tm, const void* __restrict__ am,
                             const void* __restrict__ vm, const void* __restrict__ b0,
                             const void* __restrict__ b1,
                             float* __restrict__ colsum, int* __restrict__ deg,
                             float* __restrict__ maskmul, float* __restrict__ b0f,
                             float* __restrict__ b1f, const int* __restrict__ dflag) {
    int b = blockIdx.x, t = threadIdx.x;
    if (b < 500) {
        int f32 = *dflag;
        int c = (b % 5) * 256 + t;
        if (c >= IN_F) return;
        int r0 = (b / 5) * 100;
        float s = 0.f;
        for (int r = r0; r < r0 + 100; ++r)
            s += ldin(feats, (size_t)r * IN_F + c, f32);
        atomicAdd(&colsum[c], s);
    } else if (b < 750) {
        int e = (b - 500) * 256 + t;
        if (e < N_EDGES) atomicAdd(&deg[dst[e]], 1);
    } else {
        int f32 = *dflag;
        int c = (b - 750) * 256 + t;
        if (c < IN_F) maskmul[c] = ldin(tm, c, f32) + ldin(am, c, f32) + ldin(vm, c, f32);
        if (c < HD0) b0f[c] = ldin(b0, c, f32);
        if (c < HD1) b1f[c] = ldin(b1, c, f32);
    }
}

// block-wide exclusive scan via wave shfl scan (no serial thread-0 loop)
__global__ __launch_bounds__(256) void scan_kernel(const int* __restrict__ deg,
                                                   int* __restrict__ rowptr,
                                                   int* __restrict__ cursor) {
    __shared__ int wtot[4];
    int t = threadIdx.x;
    int lane = t & 63, w = t >> 6;
    int base = t * 40;
    int s = 0;
    for (int i = 0; i < 40; ++i) {
        int idx = base + i;
        if (idx < N_NODES) s += deg[idx];
    }
    int inc = s;
#pragma unroll
    for (int d = 1; d < 64; d <<= 1) {
        int v = __shfl_up(inc, d);
        if (lane >= d) inc += v;
    }
    if (lane == 63) wtot[w] = inc;
    __syncthreads();
    int woff = 0;
    for (int ww = 0; ww < w; ++ww) woff += wtot[ww];
    int run = woff + inc - s;          // exclusive prefix for this thread
    for (int i = 0; i < 40; ++i) {
        int idx = base + i;
        if (idx < N_NODES) {
            rowptr[idx] = run; cursor[idx] = run;
            run += deg[idx];
        }
    }
    if (t == 255) rowptr[N_NODES] = woff + inc;   // grand total
}

__global__ void scatter_kernel(const int* __restrict__ dst, int* __restrict__ cursor,
                               int* __restrict__ csr_eid) {
    int e = blockIdx.x * 256 + threadIdx.x;
    if (e >= N_EDGES) return;
    int pos = atomicAdd(&cursor[dst[e]], 1);
    csr_eid[pos] = e;
}

// fused big prep (R10 form): prep_row wave-per-row (2560 blocks x 4 rows) +
// bt transpose (3840) + w2cols (160) + bt1 (384).
__global__ __launch_bounds__(256) void prepB_kernel(
        const void* __restrict__ feats, const float* __restrict__ colsum,
        const float* __restrict__ maskmul, __hip_bfloat16* __restrict__ abf,
        const void* __restrict__ Wl0, const void* __restrict__ Wr0,
        const void* __restrict__ Wres0, const void* __restrict__ W2,
        __hip_bfloat16* __restrict__ bt,
        const void* __restrict__ Wl1, const void* __restrict__ Wr1,
        const void* __restrict__ Wres1, __hip_bfloat16* __restrict__ bt1,
        const int* __restrict__ dflag) {
    __shared__ float smem[1056];
    int b = blockIdx.x, t = threadIdx.x;
    int f32 = *dflag;
    if (b < 2560) {
        int w = t >> 6, lane = t & 63;
        int n = b * 4 + w;
        unsigned short* arow = (unsigned short*)abf + (size_t)n * KPAD;
        if (n >= N_NODES) {
#pragma unroll
            for (int j = 0; j < 20; ++j) arow[j * 64 + lane] = 0;
            return;
        }
        float v[20];
        float s = 0.f;
#pragma unroll
        for (int j = 0; j < 20; ++j) {
            int c = j * 64 + lane;
            float f = (c < IN_F) ? ldin(feats, (size_t)n * IN_F + c, f32) : 0.f;
            float vv = (f != 0.0f) ? f
                     : ((c < IN_F) ? 0.5f * colsum[c] * INV_N : 0.f);  // 0.5*(h+h1)
            v[j] = vv;
            s += fabsf(vv);
        }
#pragma unroll
        for (int off = 32; off > 0; off >>= 1) s += __shfl_xor(s, off);
        float scale = 1.0f / fmaxf(s, 1e-12f);
#pragma unroll
        for (int j = 0; j < 20; ++j) {
            int c = j * 64 + lane;
            float vv = (c < IN_F) ? v[j] * scale * maskmul[c] : 0.f;
            arow[c] = f2bu(vv);
        }
    } else if (b < 2560 + 3840) {
        // LDS-tiled transpose of Wl0/Wr0/Wres0 -> bt rows 0..3071
        int b2 = b - 2560;
        int bz = b2 / 1280, rem = b2 - bz * 1280;
        int by = rem >> 5, bx = rem & 31;
        float (*tile)[33] = (float(*)[33])smem;
        int n0 = bx * 32, k0 = by * 32;
        const void* W = (bz == 0) ? Wl0 : (bz == 1) ? Wr0 : Wres0;
        int tx = t & 31, ty = t >> 5;
        for (int i = ty; i < 32; i += 8) {
            int k = k0 + i;
            tile[i][tx] = (k < IN_F) ? ldin(W, (size_t)k * HD0 + n0 + tx, f32) : 0.f;
        }
        __syncthreads();
        for (int i = ty; i < 32; i += 8)
            bt[(size_t)(bz * 1024 + n0 + i) * KPAD + k0 + tx] = __float2bfloat16(tile[tx][i]);
    } else if (b < 2560 + 3840 + 160) {
        // W2 z-columns -> bt rows 3072..3103 (coalesced over k)
        int idx = (b - (2560 + 3840)) * 256 + t;
        if (idx >= 32 * KPAD) return;
        int n = idx / KPAD, k = idx % KPAD;
        int hh = n >> 3, o = n & 7;
        float v = (k < IN_F) ? ldin(W2, ((size_t)hh * IN_F + k) * D1 + o, f32) : 0.f;
        bt[(size_t)(NBIG + n) * KPAD + k] = __float2bfloat16(v);
    } else {
        // bt1 [96][1024], coalesced writes
        int idx = (b - (2560 + 4000)) * 256 + t;
        if (idx >= 96 * HD0) return;
        int n = idx >> 10, k = idx & 1023;
        int seg = n >> 5, col = n & 31;
        const void* W = (seg == 0) ? Wl1 : (seg == 1) ? Wr1 : Wres1;
        bt1[idx] = __float2bfloat16(ldin(W, (size_t)k * HD1 + col, f32));
    }
}

// MFMA GEMM (FROZEN at R13 best: 138.9us): C[MPAD x 3072] = abf @ bt^T (main)
// + z strip (bt rows 3072..3103).  512 blocks = 480 main + 32 z (2 perfect
// occupancy rounds; z hidden in round-2 slack).  Fine-interleave + counted
// vmcnt(4), 3-slot BK=32, 8 waves, XCD swizzle.
__global__ __launch_bounds__(512) void mfma_gemm(
        const unsigned short* __restrict__ A, const unsigned short* __restrict__ BT,
        const float* __restrict__ b0f, __hip_bfloat16* __restrict__ fs0b,
        __hip_bfloat16* __restrict__ fd0b, __hip_bfloat16* __restrict__ out0r,
        float* __restrict__ z) {
    __shared__ unsigned short As0[8192], Bs0[8192];   // slot 0 (16KB + 16KB)
    __shared__ unsigned short As1[8192], Bs1[8192];   // slot 1
    __shared__ unsigned short As2[8192], Bs2[8192];   // slot 2  (96KB)
    const int g = blockIdx.x;
    const int tid = threadIdx.x;
    const int wave = tid >> 6, lane = tid & 63;
    const int quad = lane >> 4, l16 = lane & 15;
    const int srow = lane & 15;
    const int skc  = (lane >> 4) * 8;

    if (g >= 480) {
        // ---- z strip: 320 rows x 32 cols (BT rows 3072..3103), K=1280 ----
        int zb = g - 480;                                  // [0,32)
        int rbase = zb * 320 + wave * 40;                  // 8 waves x 40 rows
        int r0 = rbase + srow;
        int r1 = rbase + 16 + srow;
        int r2 = rbase + 32 + srow;
        r2 = r2 < MPAD ? r2 : (MPAD - 1);                  // clamp to zeroed pad
        const unsigned short* B0p = BT + (size_t)(NBIG + srow) * KPAD;
        const unsigned short* B1p = BT + (size_t)(NBIG + 16 + srow) * KPAD;
        f32x4 zacc[3][2];
#pragma unroll
        for (int i = 0; i < 3; ++i)
#pragma unroll
            for (int j = 0; j < 2; ++j) zacc[i][j] = (f32x4){0.f, 0.f, 0.f, 0.f};
#pragma unroll 2
        for (int kk = 0; kk < KPAD; kk += 32) {
            bf16x8 a0 = *(const bf16x8*)(A + (size_t)r0 * KPAD + kk + skc);
            bf16x8 a1 = *(const bf16x8*)(A + (size_t)r1 * KPAD + kk + skc);
            bf16x8 a2 = *(const bf16x8*)(A + (size_t)r2 * KPAD + kk + skc);
            bf16x8 b0 = *(const bf16x8*)(B0p + kk + skc);
            bf16x8 b1 = *(const bf16x8*)(B1p + kk + skc);
            zacc[0][0] = __builtin_amdgcn_mfma_f32_16x16x32_bf16(a0, b0, zacc[0][0], 0, 0, 0);
            zacc[0][1] = __builtin_amdgcn_mfma_f32_16x16x32_bf16(a0, b1, zacc[0][1], 0, 0, 0);
            zacc[1][0] = __builtin_amdgcn_mfma_f32_16x16x32_bf16(a1, b0, zacc[1][0], 0, 0, 0);
            zacc[1][1] = __builtin_amdgcn_mfma_f32_16x16x32_bf16(a1, b1, zacc[1][1], 0, 0, 0);
            zacc[2][0] = __builtin_amdgcn_mfma_f32_16x16x32_bf16(a2, b0, zacc[2][0], 0, 0, 0);
            zacc[2][1] = __builtin_amdgcn_mfma_f32_16x16x32_bf16(a2, b1, zacc[2][1], 0, 0, 0);
        }
#pragma unroll
        for (int rf = 0; rf < 3; ++rf)
#pragma unroll
            for (int r = 0; r < 4; ++r) {
                int gm = rbase + rf * 16 + quad * 4 + r;
                if (gm >= N_NODES) continue;
#pragma unroll
                for (int cf = 0; cf < 2; ++cf)
                    z[(size_t)gm * HD1 + cf * 16 + l16] = zacc[rf][cf][r];
            }
        return;
    }

    // ---- main path: 480 blocks = 8 XCD x 60 (5 row x 12 col) ----
    const int xcd = g & 7, l = g >> 3;          // l in [0,60)
    const int colt = l / 5, rowi = l - colt * 5;
    const int bm = (xcd * 5 + rowi) * 256;
    const int bn = colt * 256;
    const int wr = wave >> 2, wc = wave & 3;    // 2 x 4 wave grid
    const int wm = wr * 128, wn = wc * 64;

    f32x4 acc[8][4];
#pragma unroll
    for (int i = 0; i < 8; ++i)
#pragma unroll
        for (int j = 0; j < 4; ++j) acc[i][j] = (f32x4){0.f, 0.f, 0.f, 0.f};

#define BARX() do { __builtin_amdgcn_s_barrier();                            \
                    __builtin_amdgcn_sched_barrier(0); } while (0)

#define STAGE_A2(kt, dst) do {                                               \
        _Pragma("unroll")                                                    \
        for (int tt = 0; tt < 2; ++tt) {                                     \
            int gg = wave + 8 * tt;                                          \
            async_copy16(A + (size_t)(bm + gg * 16 + srow) * KPAD            \
                             + (kt) + skc,                                   \
                         (dst) + gg * 512);                                  \
        } } while (0)

#define STAGE_B2(kt, dst) do {                                               \
        _Pragma("unroll")                                                    \
        for (int tt = 0; tt < 2; ++tt) {                                     \
            int gg = wave + 8 * tt;                                          \
            async_copy16(BT + (size_t)(bn + gg * 16 + srow) * KPAD           \
                             + (kt) + skc,                                   \
                         (dst) + gg * 512);                                  \
        } } while (0)

#define LOADAF(buf) do {                                                     \
        _Pragma("unroll")                                                    \
        for (int fb = 0; fb < 8; ++fb)                                       \
            af[fb] = *(const bf16x8*)((buf) + (wr * 8 + fb) * 512            \
                                      + lane * 8);                           \
    } while (0)

#define LOADBF(buf, half) do {                                               \
        _Pragma("unroll")                                                    \
        for (int jj = 0; jj < 2; ++jj)                                       \
            bfr[jj] = *(const bf16x8*)((buf) + (wc * 4 + (half) * 2 + jj)    \
                                       * 512 + lane * 8);                    \
    } while (0)

#define MFMA16(jb) do {                                                      \
        __builtin_amdgcn_s_setprio(1);                                       \
        _Pragma("unroll")                                                    \
        for (int fb = 0; fb < 8; ++fb) {                                     \
            acc[fb][(jb)]     = __builtin_amdgcn_mfma_f32_16x16x32_bf16(     \
                af[fb], bfr[0], acc[fb][(jb)], 0, 0, 0);                     \
            acc[fb][(jb) + 1] = __builtin_amdgcn_mfma_f32_16x16x32_bf16(     \
                af[fb], bfr[1], acc[fb][(jb) + 1], 0, 0, 0);                 \
        }                                                                    \
        __builtin_amdgcn_s_setprio(0);                                       \
    } while (0)

#define KSTEP(curA, curB, preA, preB, kt, dostage, endcnt) do {              \
        bf16x8 af[8], bfr[2];                                                \
        LOADAF(curA);                                                        \
        LOADBF(curB, 0);                                                     \
        if (dostage) STAGE_A2((kt), preA);                                   \
        BARX();                                                              \
        MFMA16(0);                                                           \
        BARX();                                                              \
        LOADBF(curB, 1);                                                     \
        if (dostage) STAGE_B2((kt), preB);                                   \
        BARX();                                                              \
        MFMA16(2);                                                           \
        asm volatile("s_waitcnt vmcnt(" #endcnt ")" ::: "memory");           \
        BARX();                                                              \
    } while (0)

    STAGE_A2(0, As0);  STAGE_B2(0, Bs0);
    STAGE_A2(32, As1); STAGE_B2(32, Bs1);
    asm volatile("s_waitcnt vmcnt(4)" ::: "memory");
    BARX();

    for (int m = 0; m < 36; m += 3) {
        KSTEP(As0, Bs0, As2, Bs2, (m + 2) * 32, 1, 4);   // u=m
        KSTEP(As1, Bs1, As0, Bs0, (m + 3) * 32, 1, 4);   // u=m+1
        KSTEP(As2, Bs2, As1, Bs1, (m + 4) * 32, 1, 4);   // u=m+2
    }
    KSTEP(As0, Bs0, As2, Bs2, 38 * 32, 1, 4);   // u=36: stage t38 -> slot2
    KSTEP(As1, Bs1, As0, Bs0, 39 * 32, 1, 4);   // u=37: stage t39 -> slot0
    KSTEP(As2, Bs2, As0, Bs0, 0,       0, 0);   // u=38: t38, drain t39
    KSTEP(As0, Bs0, As1, Bs1, 0,       0, 0);   // u=39: t39
#undef KSTEP
#undef MFMA16
#undef LOADBF
#undef LOADAF
#undef STAGE_B2
#undef STAGE_A2
#undef BARX

    const int seg = bn >> 10;   // 0,1,2 only (bn <= 2816)
#pragma unroll
    for (int i = 0; i < 8; ++i) {
#pragma unroll
        for (int r = 0; r < 4; ++r) {
            int gm = bm + wm + i * 16 + quad * 4 + r;
            if (gm >= N_NODES) continue;
#pragma unroll
            for (int j = 0; j < 4; ++j) {
                int gnl = (bn & 1023) + wn + j * 16 + l16;
                float v = acc[i][j][r];
                if (seg == 0)      fs0b[(size_t)gm * HD0 + gnl] = __float2bfloat16(v);
                else if (seg == 1) fd0b[(size_t)gm * HD0 + gnl] = __float2bfloat16(v);
                else               out0r[(size_t)gm * HD0 + gnl] = __float2bfloat16(v + b0f[gnl]);
            }
        }
    }
}

// merged layer-0 attention (blocks 0..9999) + gat_inner attention
// (blocks 10000..11249).  R14: sfd/sa0 are PER-THREAD (written and read only
// at 4t..4t+3 by thread t) -- moved from LDS to registers; plus software
// prefetch of the next edge's source row (one full iteration of L2/L3
// latency hidden beyond TLP).
__global__ __launch_bounds__(256) void att0z_kernel(
        const int* __restrict__ rowptr, const int* __restrict__ csre,
        const int* __restrict__ src, const __hip_bfloat16* __restrict__ fs,
        const __hip_bfloat16* __restrict__ fd, const void* __restrict__ a0,
        const __hip_bfloat16* __restrict__ out0res, __hip_bfloat16* __restrict__ out0b,
        const float* __restrict__ z, const void* __restrict__ a2,
        float* __restrict__ h3, const int* __restrict__ dflag) {
    int f32 = *dflag;
    if (blockIdx.x >= N_NODES) {
        // ---- att32z path (prefetched) ----
        int n = (blockIdx.x - N_NODES) * 8 + (threadIdx.x >> 5);
        int lane = threadIdx.x & 31;
        int h = lane >> 3, o = lane & 7;
        float a2e = ldin(a2, h * 2 * D1 + o, f32);        // es half
        float a2d = ldin(a2, h * 2 * D1 + D1 + o, f32);   // ed half
        float zn = z[(size_t)n * HD1 + lane];
        float edn = zn * a2d;
        edn += __shfl_xor(edn, 1); edn += __shfl_xor(edn, 2); edn += __shfl_xor(edn, 4);
        float den = 0.f, acc = 0.f;
        int start = rowptr[n], end = rowptr[n + 1];
        int deg = end - start;
        float zsN = 0.f;
        if (deg > 0) zsN = z[(size_t)src[csre[start]] * HD1 + lane];
        for (int i = 0; i < deg; ++i) {
            float zs = zsN;
            if (i + 1 < deg)
                zsN = z[(size_t)src[csre[start + i + 1]] * HD1 + lane];
            float esv = zs * a2e;
            esv += __shfl_xor(esv, 1); esv += __shfl_xor(esv, 2); esv += __shfl_xor(esv, 4);
            float x = esv + edn;
            x = x > 0.f ? x : 0.2f * x;
            float p = expf(x);
            den += p;
            acc += p * zs;
        }
        h3[(size_t)n * HD1 + lane] = acc / fmaxf(den, 1e-9f);
        return;
    }
    // ---- att0 path ----
    int n = blockIdx.x;
    int t = threadIdx.x;
    __shared__ int sidx[128];
    int start = rowptr[n], end = rowptr[n + 1];
    int deg = end - start;
    // per-thread state in registers (sfd/sa0 were thread-private in LDS)
    float rfd[4], ra0[4];
    {
        const unsigned short* fdp = (const unsigned short*)fd + (size_t)n * HD0;
        ushort4 u = *(const ushort4*)(fdp + 4 * t);
        rfd[0] = bfu2f(u.x); rfd[1] = bfu2f(u.y);
        rfd[2] = bfu2f(u.z); rfd[3] = bfu2f(u.w);
#pragma unroll
        for (int i = 0; i < 4; ++i) ra0[i] = ldin(a0, 4 * t + i, f32);
        if (t < deg && t < 128) sidx[t] = src[csre[start + t]];
    }
    __syncthreads();
    const unsigned short* fsu = (const unsigned short*)fs;
    float den = 0.f;
    float acc[4] = {0.f, 0.f, 0.f, 0.f};
    // software prefetch pipeline: next edge's row load issued before the
    // current edge's reduce chain.
    ushort4 uN;
    if (deg > 0) {
        int s0 = sidx[0];
        uN = *(const ushort4*)(fsu + (size_t)s0 * HD0 + 4 * t);
    }
    for (int i = 0; i < deg; ++i) {
        ushort4 u = uN;
        if (i + 1 < deg) {
            int sn = (i + 1 < 128) ? sidx[i + 1] : src[csre[start + i + 1]];
            uN = *(const ushort4*)(fsu + (size_t)sn * HD0 + 4 * t);
        }
        float fv[4], part = 0.f;
#pragma unroll
        for (int j = 0; j < 4; ++j) {
            unsigned short uj = (j == 0) ? u.x : (j == 1) ? u.y : (j == 2) ? u.z : u.w;
            fv[j] = bfu2f(uj);
            float x = fv[j] + rfd[j];
            x = x > 0.f ? x : 0.2f * x;
            part += x * ra0[j];
        }
        for (int off = 32; off > 0; off >>= 1) part += __shfl_xor(part, off);
        float p = expf(part);
        den += p;   // identical across the wave (= head)
#pragma unroll
        for (int j = 0; j < 4; ++j) acc[j] += p * fv[j];
    }
    float inv = 1.0f / fmaxf(den, 1e-9f);
    ushort4 ub = *(const ushort4*)((const unsigned short*)out0res + (size_t)n * HD0 + 4 * t);
    ushort4 o;
    o.x = f2bu(fmaxf(bfu2f(ub.x) + acc[0] * inv, 0.f));
    o.y = f2bu(fmaxf(bfu2f(ub.y) + acc[1] * inv, 0.f));
    o.z = f2bu(fmaxf(bfu2f(ub.z) + acc[2] * inv, 0.f));
    o.w = f2bu(fmaxf(bfu2f(ub.w) + acc[3] * inv, 0.f));
    *(ushort4*)((unsigned short*)out0b + (size_t)n * HD0 + 4 * t) = o;
}

// layer-1 fused MFMA GEMM, 2-way K-SPLIT: blocks [0,157) compute K 0..511,
// blocks [157,314) compute K 512..1023 into partial buffers (abf region, dead
// after the big GEMM).  att32e_final sums the partial pairs.
__global__ __launch_bounds__(256) void mfma_gemm96(
        const unsigned short* __restrict__ A, const unsigned short* __restrict__ BT1,
        const float* __restrict__ b1f, float* __restrict__ fs1,
        float* __restrict__ fd1, float* __restrict__ out1,
        float* __restrict__ fs1b, float* __restrict__ fd1b,
        float* __restrict__ out1b) {
    __shared__ unsigned short As0[2048], Bs0[3072], As1[2048], Bs1[3072];  // 20KB
    const int tid = threadIdx.x;
    const int wave = tid >> 6, lane = tid & 63;
    const int quad = lane >> 4, l16 = lane & 15;
    const int bk = blockIdx.x >= 157;           // K-half
    const int bm = (blockIdx.x - (bk ? 157 : 0)) * 64;
    const int kbase = bk ? 512 : 0;
    const int srow = lane & 15;
    const int skc  = (lane >> 4) * 8;
    const int NIT = 512 / 32;   // 16 (even)

    f32x4 acc[6];
#pragma unroll
    for (int j = 0; j < 6; ++j) acc[j] = (f32x4){0.f, 0.f, 0.f, 0.f};

#define STAGE96(kk, Adst, Bdst) do {                                              \
        async_copy16(A + (size_t)(bm + wave * 16 + srow) * HD0 + kbase + (kk) + skc, \
                     (Adst) + wave * 512);                                        \
        async_copy16(BT1 + (size_t)(wave * 16 + srow) * HD0 + kbase + (kk) + skc, \
                     (Bdst) + wave * 512);                                        \
        if (wave < 2)                                                             \
            async_copy16(BT1 + (size_t)((4 + wave) * 16 + srow) * HD0 + kbase + (kk) + skc, \
                         (Bdst) + (4 + wave) * 512);                              \
        } while (0)

#define COMPUTE96(Asrc, Bsrc) do {                                                \
        bf16x8 af = *(const bf16x8*)((Asrc) + wave * 512 + lane * 8);             \
        _Pragma("unroll")                                                         \
        for (int j = 0; j < 6; ++j) {                                             \
            bf16x8 bfr = *(const bf16x8*)((Bsrc) + j * 512 + lane * 8);           \
            acc[j] = __builtin_amdgcn_mfma_f32_16x16x32_bf16(af, bfr, acc[j], 0, 0, 0); \
        } } while (0)

    STAGE96(0, As0, Bs0);
    for (int it = 0; it < NIT; it += 2) {
        asm volatile("s_waitcnt vmcnt(0)" ::: "memory");
        asm volatile("s_barrier" ::: "memory");
        STAGE96((it + 1) * 32, As1, Bs1);
        COMPUTE96(As0, Bs0);
        asm volatile("s_waitcnt vmcnt(0)" ::: "memory");
        asm volatile("s_barrier" ::: "memory");
        if (it + 2 < NIT) STAGE96((it + 2) * 32, As0, Bs0);
        COMPUTE96(As1, Bs1);
    }
#undef STAGE96
#undef COMPUTE96

#pragma unroll
    for (int r = 0; r < 4; ++r) {
        int gm = bm + wave * 16 + quad * 4 + r;
        if (gm >= N_NODES) continue;
#pragma unroll
        for (int j = 0; j < 6; ++j) {
            int col = j * 16 + l16;
            int seg = col >> 5, cl = col & 31;
            float v = acc[j][r];
            if (!bk) {
                if (seg == 0)      fs1[(size_t)gm * HD1 + cl] = v;
                else if (seg == 1) fd1[(size_t)gm * HD1 + cl] = v;
                else               out1[(size_t)gm * HD1 + cl] = v + b1f[cl];
            } else {
                if (seg == 0)      fs1b[(size_t)gm * HD1 + cl] = v;
                else if (seg == 1) fd1b[(size_t)gm * HD1 + cl] = v;
                else               out1b[(size_t)gm * HD1 + cl] = v;
            }
        }
    }
}

// layer-1 attention + final linear fused, 8 nodes per 256-block.
// Sums the K-split partial pairs from mfma_gemm96.  R14: prefetch next edge.
__global__ __launch_bounds__(256) void att32e_final_kernel(
        const int* __restrict__ rowptr, const int* __restrict__ csre,
        const int* __restrict__ src, const float* __restrict__ fs1,
        const float* __restrict__ fd1, const void* __restrict__ a1,
        const float* __restrict__ out1g, const float* __restrict__ h3,
        const void* __restrict__ Wlin, const void* __restrict__ blin,
        void* __restrict__ out, const int* __restrict__ dflag,
        const float* __restrict__ fs1b, const float* __restrict__ fd1b,
        const float* __restrict__ out1gb) {
    int f32 = *dflag;
    int n = blockIdx.x * 8 + (threadIdx.x >> 5);
    int lane = threadIdx.x & 31;
    size_t ni = (size_t)n * HD1 + lane;
    float fdn = fd1[ni] + fd1b[ni];
    float a = ldin(a1, lane, f32);            // a1[h][o], lane = h*8+o
    float den = 0.f, acc = 0.f;
    int start = rowptr[n], end = rowptr[n + 1];
    int deg = end - start;
    float fsN = 0.f;
    if (deg > 0) {
        size_t s0 = (size_t)src[csre[start]] * HD1 + lane;
        fsN = fs1[s0] + fs1b[s0];
    }
    for (int i = 0; i < deg; ++i) {
        float fsv = fsN;
        if (i + 1 < deg) {
            size_t sn = (size_t)src[csre[start + i + 1]] * HD1 + lane;
            fsN = fs1[sn] + fs1b[sn];
        }
        float x = fsv + fdn;
        x = x > 0.f ? x : 0.2f * x;
        float term = x * a;
        term += __shfl_xor(term, 1);
        term += __shfl_xor(term, 2);
        term += __shfl_xor(term, 4);          // head-wide logit (8 lanes/oct)
        float p = expf(term);
        den += p;
        acc += p * fsv;
    }
    float out1v = fmaxf(out1g[ni] + out1gb[ni] + acc / fmaxf(den, 1e-9f), 0.f);
    float h3v = h3[ni];
    float partial[OUTF];
#pragma unroll
    for (int o = 0; o < OUTF; ++o)
        partial[o] = h3v * ldin(Wlin, (size_t)lane * OUTF + o, f32)
                   + out1v * ldin(Wlin, (size_t)(HD1 + lane) * OUTF + o, f32);
#pragma unroll
    for (int st = 1; st <= 16; st <<= 1)
#pragma unroll
        for (int o = 0; o < OUTF; ++o) partial[o] += __shfl_xor(partial[o], st);
    if (lane == 0) {
#pragma unroll
        for (int o = 0; o < OUTF; ++o) {
            float v = partial[o] + ldin(blin, o, f32);
            if (f32) ((float*)out)[(size_t)n * OUTF + o] = v;
            else     ((__hip_bfloat16*)out)[(size_t)n * OUTF + o] = __float2bfloat16(v);
        }
    }
}

// ---------------- launch ----------------
extern "C" void kernel_launch(void* const* d_in, const int* in_sizes, int n_in,
                              void* d_out, int out_size, void* d_ws, size_t ws_size,
                              hipStream_t stream) {
    const void* feats = d_in[0];
    const int*  src   = (const int*)d_in[1];
    const int*  dst   = (const int*)d_in[2];
    const void* tm    = d_in[3];
    const void* am    = d_in[4];
    const void* vm    = d_in[5];
    const void* W2    = d_in[6];
    const void* a2    = d_in[7];
    const void* Wl0   = d_in[8];
    const void* Wr0   = d_in[9];
    const void* a0    = d_in[10];
    const void* Wres0 = d_in[11];
    const void* b0    = d_in[12];
    const void* Wl1   = d_in[13];
    const void* Wr1   = d_in[14];
    const void* a1    = d_in[15];
    const void* Wres1 = d_in[16];
    const void* b1    = d_in[17];
    const void* Wlin  = d_in[18];
    const void* blin  = d_in[19];

    float* ws = (float*)d_ws;
    int*   dflag  = (int*)(ws + OFF_FLAG);
    float* colsum = ws + OFF_COLSUM;
    float* maskm  = ws + OFF_MASKM;
    float* z      = ws + OFF_Z;
    float* h3     = ws + OFF_H3;
    float* fs1    = ws + OFF_FS1;
    float* fd1    = ws + OFF_FD1;
    float* out1   = ws + OFF_OUT1;
    float* b0f    = ws + OFF_B0F;
    float* b1f    = ws + OFF_B1F;
    int*   deg    = (int*)(ws + OFF_DEG);
    int*   rowptr = (int*)(ws + OFF_ROWPTR);
    int*   cursor = (int*)(ws + OFF_CURSOR);
    int*   csre   = (int*)(ws + OFF_CSRE);
    __hip_bfloat16* out0r = (__hip_bfloat16*)(ws + OFF_OUT0);
    __hip_bfloat16* fs0b = (__hip_bfloat16*)(ws + OFF_FS0B);
    __hip_bfloat16* fd0b = (__hip_bfloat16*)(ws + OFF_FD0B);
    __hip_bfloat16* abf  = (__hip_bfloat16*)(ws + OFF_ABF);
    __hip_bfloat16* bt   = (__hip_bfloat16*)(ws + OFF_BT);
    __hip_bfloat16* bt1  = (__hip_bfloat16*)(ws + OFF_BT1);
    __hip_bfloat16* out0b = fd0b;   // fd0b row n retired after att0 block n reads it
    // K-split partials for gemm96 -- placed in the abf region (dead after the
    // big GEMM completes; gemm96 runs two dispatches later).
    float* fs1b  = ws + OFF_ABF;
    float* fd1b  = ws + OFF_ABF + 320000;
    float* out1b = ws + OFF_ABF + 640000;

    // single memset: dflag + colsum (contiguous). Other zeroing in init_kernel.
    (void)hipMemsetAsync(ws, 0, (16 + 1280) * sizeof(float), stream);

    // init: detect + deg-zero
    init_kernel<<<104, 256, 0, stream>>>((const unsigned short*)feats, dflag, deg);
    // colsum (500) + deg histogram (250) + small preps (5)
    prepA_kernel<<<755, 256, 0, stream>>>(feats, dst, tm, am, vm, b0, b1,
                                          colsum, deg, maskm, b0f, b1f, dflag);
    scan_kernel<<<1, 256, 0, stream>>>(deg, rowptr, cursor);
    scatter_kernel<<<(N_EDGES + 255) / 256, 256, 0, stream>>>(dst, cursor, csre);

    // big prep: A rows (wave-per-row) + weight transposes + w2cols
    prepB_kernel<<<2560 + 3840 + 160 + 384, 256, 0, stream>>>(
        feats, colsum, maskm, abf, Wl0, Wr0, Wres0, W2, bt, Wl1, Wr1, Wres1,
        bt1, dflag);

    // big fused projection GEMM: 480 main + 32 z-strip blocks = 512 = exactly
    // 2 occupancy rounds; z hidden in round-2 slack (frozen at R13 best)
    mfma_gemm<<<512, 512, 0, stream>>>(
        (const unsigned short*)abf, (const unsigned short*)bt, b0f, fs0b, fd0b,
        out0r, z);

    // GATv2 layer 0 attention + gat_inner attention (merged dispatch)
    att0z_kernel<<<N_NODES + N_NODES / 8, 256, 0, stream>>>(
        rowptr, csre, src, fs0b, fd0b, a0, out0r, out0b, z, a2, h3, dflag);

    // GATv2 layer 1 GEMM, 2-way K-split (314 blocks)
    mfma_gemm96<<<314, 256, 0, stream>>>(
        (const unsigned short*)out0b, (const unsigned short*)bt1, b1f,
        fs1, fd1, out1, fs1b, fd1b, out1b);

    // layer-1 attention + final linear fused (sums K-split partials)
    att32e_final_kernel<<<N_NODES / 8, 256, 0, stream>>>(
        rowptr, csre, src, fs1, fd1, a1, out1, h3, Wlin, blin, d_out, dflag,
        fs1b, fd1b, out1b);
}